// Round 4
// baseline (1420.270 us; speedup 1.0000x reference)
//
#include <hip/hip_runtime.h>

#define NN 100000
#define EE 3200000
#define N2 100032   // NN rounded up to 64
#define NBUCK 782   // ceil(NN/128)

typedef _Float16 f16;
typedef _Float16 f16x8 __attribute__((ext_vector_type(8)));
typedef float f32x4 __attribute__((ext_vector_type(4)));
typedef unsigned int u32;

#define MFMA(a, b, c) __builtin_amdgcn_mfma_f32_16x16x32_f16((a), (b), (c), 0, 0, 0)

// ---------------- CSR build (binned two-phase) ----------------

__global__ __launch_bounds__(256) void bhist_kernel(const int* __restrict__ dst,
                                                    int* __restrict__ bcnt) {
  __shared__ int h[NBUCK];
  int tid = threadIdx.x;
  for (int i = tid; i < NBUCK; i += 256) h[i] = 0;
  __syncthreads();
  for (int e = blockIdx.x * 256 + tid; e < EE; e += gridDim.x * 256)
    atomicAdd(&h[dst[e] >> 7], 1);
  __syncthreads();
  for (int i = tid; i < NBUCK; i += 256) {
    int v = h[i];
    if (v) atomicAdd(&bcnt[i], v);
  }
}

__global__ __launch_bounds__(1024) void bscan_kernel(const int* __restrict__ bcnt,
                                                     int* __restrict__ bbase,
                                                     int* __restrict__ bcur,
                                                     int* __restrict__ rs) {
  __shared__ int sb[1024];
  int tid = threadIdx.x;
  int c = (tid < NBUCK) ? bcnt[tid] : 0;
  int v = c;
  sb[tid] = v;
  __syncthreads();
  for (int off = 1; off < 1024; off <<= 1) {
    int t = (tid >= off) ? sb[tid - off] : 0;
    __syncthreads();
    v += t;
    sb[tid] = v;
    __syncthreads();
  }
  if (tid < NBUCK) {
    bbase[tid] = v - c;
    bcur[tid] = v - c;
  }
  if (tid == 0) {
    bbase[NBUCK] = EE;
    rs[NN] = EE;
  }
}

__global__ __launch_bounds__(256) void binB_kernel(const int* __restrict__ src,
                                                   const int* __restrict__ dst,
                                                   int* __restrict__ bcur,
                                                   u32* __restrict__ ebuf) {
  int e = blockIdx.x * 256 + threadIdx.x;
  if (e < EE) {
    int d = dst[e];
    int pos = atomicAdd(&bcur[d >> 7], 1);
    ebuf[pos] = (u32)src[e] | ((u32)(d & 127) << 17);
  }
}

__global__ __launch_bounds__(256) void binC_kernel(const u32* __restrict__ ebuf,
                                                   const int* __restrict__ bbase,
                                                   int* __restrict__ rs,
                                                   int* __restrict__ csr) {
  __shared__ int cnt[128], sc[128], cur[128];
  int b = blockIdx.x, tid = threadIdx.x;
  int e0 = bbase[b], e1 = bbase[b + 1];
  if (tid < 128) cnt[tid] = 0;
  __syncthreads();
  for (int e = e0 + tid; e < e1; e += 256) atomicAdd(&cnt[ebuf[e] >> 17], 1);
  __syncthreads();
  if (tid < 128) sc[tid] = cnt[tid];
  __syncthreads();
  for (int off = 1; off < 128; off <<= 1) {
    int t = 0;
    if (tid < 128 && tid >= off) t = sc[tid - off];
    __syncthreads();
    if (tid < 128) sc[tid] += t;
    __syncthreads();
  }
  if (tid < 128) {
    int gpos = e0 + sc[tid] - cnt[tid];
    int node = b * 128 + tid;
    if (node < NN) rs[node] = gpos;
    cur[tid] = gpos;
  }
  __syncthreads();
  for (int e = e0 + tid; e < e1; e += 256) {
    u32 p = ebuf[e];
    int pos = atomicAdd(&cur[p >> 17], 1);
    csr[pos] = (int)(p & 0x1FFFFu);
  }
}

// ---------------- weight pack into B-fragment order ----------------

__global__ __launch_bounds__(256) void pack_kernel(const float* __restrict__ W, int K, int Nc,
                                                   int KG, int NB, int trans,
                                                   f16* __restrict__ dst) {
  int i = blockIdx.x * 256 + threadIdx.x;
  if (i >= NB * KG * 128) return;
  int e = i & 7, nn = (i >> 3) & 15;
  int g = (i >> 7) % KG, nb = (i >> 7) / KG;
  int k = g * 8 + e, n = nb * 16 + nn;
  float v = 0.f;
  if (k < K && n < Nc) v = trans ? W[n * K + k] : W[k * Nc + n];
  dst[i] = (f16)v;
}

// ---------------- x -> padded f16 ----------------

__global__ __launch_bounds__(256) void convx_kernel(const float* __restrict__ x,
                                                    f16* __restrict__ xp) {
  int i = blockIdx.x * 256 + threadIdx.x;
  if (i >= N2 * 96) return;
  int r = i / 96, c = i - r * 96;
  xp[i] = (f16)((r < NN && c < 75) ? x[r * 75 + c] : 0.f);
}

// ---------------- aggregation: wave per node, 10 lanes x 16B, 6 edges in flight ----------------

__global__ __launch_bounds__(256) void aggz_kernel(const f16* __restrict__ xc,
                                                   const int* __restrict__ rs,
                                                   const int* __restrict__ csr,
                                                   const float* __restrict__ eps,
                                                   f16* __restrict__ zm) {
  int tid = threadIdx.x;
  int l = tid & 63;
  int n = blockIdx.x * 4 + (tid >> 6);
  if (n >= NN) return;
  int s = l / 10, j = l - s * 10;
  int e0 = rs[n], e1 = rs[n + 1];
  float acc[8] = {0, 0, 0, 0, 0, 0, 0, 0};
  if (l < 60) {
#pragma unroll 2
    for (int e = e0 + s; e < e1; e += 6) {
      int sr = csr[e];
      f16x8 v = *(const f16x8*)(xc + sr * 96 + j * 8);
#pragma unroll
      for (int k = 0; k < 8; ++k) acc[k] += (float)v[k];
    }
  }
  int l1 = (l + 30) & 63, l2 = (l + 10) & 63, l3 = (l + 20) & 63;
#pragma unroll
  for (int k = 0; k < 8; ++k) {
    float t = __shfl(acc[k], l1, 64);
    if (l < 30) acc[k] += t;              // s0..2 += s3..5
    t = __shfl(acc[k], l2, 64);
    if (l < 10) acc[k] += t;              // s0 += s1
    t = __shfl(acc[k], l3, 64);
    if (l < 10) acc[k] += t;              // s0 += s2
  }
  if (l < 10) {
    f16x8 self = *(const f16x8*)(xc + n * 96 + j * 8);
    float ep = 1.f + eps[0];
    f16x8 o;
#pragma unroll
    for (int k = 0; k < 8; ++k) o[k] = (f16)(ep * (float)self[k] + acc[k]);
    *(f16x8*)(zm + n * 96 + j * 8) = o;
  }
}

// ---------------- fused GIN MLP (in-place zm: z -> m), MFMA ----------------

__global__ __launch_bounds__(256) void mlp_kernel(f16* __restrict__ zm,
                                                  const f16* __restrict__ w1p,
                                                  const f16* __restrict__ w2p,
                                                  const float* __restrict__ b1,
                                                  const float* __restrict__ b2) {
  __shared__ f16 m1lds[4][16 * 104];
  int tid = threadIdx.x;
  int w = tid >> 6, l = tid & 63, lm = l & 15, lg = l >> 4;
  int row = blockIdx.x * 64 + w * 16 + lm;
  const f16* ar = zm + row * 96;
  f16x8 a0 = *(const f16x8*)(ar + lg * 8);
  f16x8 a1 = *(const f16x8*)(ar + 32 + lg * 8);
  f16x8 a2 = *(const f16x8*)(ar + 64 + lg * 8);
  f32x4 acc[5];
#pragma unroll
  for (int nb = 0; nb < 5; ++nb) {
    int n = nb * 16 + lm;
    float bv = (n < 75) ? b1[n] : 0.f;
    acc[nb] = (f32x4){bv, bv, bv, bv};
    const f16* bp = w1p + ((nb * 12 + lg) * 16 + lm) * 8;
    acc[nb] = MFMA(a0, *(const f16x8*)bp, acc[nb]);
    acc[nb] = MFMA(a1, *(const f16x8*)(bp + 512), acc[nb]);
    acc[nb] = MFMA(a2, *(const f16x8*)(bp + 1024), acc[nb]);
  }
  f16* Ld = m1lds[w];
#pragma unroll
  for (int nb = 0; nb < 5; ++nb)
#pragma unroll
    for (int r = 0; r < 4; ++r)
      Ld[(lg * 4 + r) * 104 + nb * 16 + lm] = (f16)fmaxf(acc[nb][r], 0.f);
#pragma unroll
  for (int c = 0; c < 4; ++c) Ld[lm * 104 + 80 + lg * 4 + c] = (f16)0.f;  // zero cols 80..95
  __syncthreads();
  const f16* Lr = m1lds[w] + lm * 104;
  f16x8 c0 = *(const f16x8*)(Lr + lg * 8);
  f16x8 c1 = *(const f16x8*)(Lr + 32 + lg * 8);
  f16x8 c2 = *(const f16x8*)(Lr + 64 + lg * 8);
  f32x4 acc2[5];
#pragma unroll
  for (int nb = 0; nb < 5; ++nb) {
    int n = nb * 16 + lm;
    float bv = (n < 75) ? b2[n] : 0.f;
    acc2[nb] = (f32x4){bv, bv, bv, bv};
    const f16* bp = w2p + ((nb * 12 + lg) * 16 + lm) * 8;
    acc2[nb] = MFMA(c0, *(const f16x8*)bp, acc2[nb]);
    acc2[nb] = MFMA(c1, *(const f16x8*)(bp + 512), acc2[nb]);
    acc2[nb] = MFMA(c2, *(const f16x8*)(bp + 1024), acc2[nb]);
  }
  f16* orow = zm + (blockIdx.x * 64 + w * 16) * 96;
#pragma unroll
  for (int nb = 0; nb < 5; ++nb)
#pragma unroll
    for (int r = 0; r < 4; ++r)
      orow[(lg * 4 + r) * 96 + nb * 16 + lm] = (f16)fmaxf(acc2[nb][r], 0.f);
}

// ---------------- GRU step, MFMA ----------------

__global__ __launch_bounds__(256) void gru_kernel(const f16* __restrict__ zm,
                                                  const f16* __restrict__ hcur,
                                                  const f16* __restrict__ wihp,
                                                  const f16* __restrict__ whhp,
                                                  const float* __restrict__ bih,
                                                  const float* __restrict__ bhh,
                                                  f16* __restrict__ xnext,
                                                  f16* __restrict__ catb, int itoff,
                                                  float* __restrict__ outx) {
  int tid = threadIdx.x;
  int w = tid >> 6, l = tid & 63, lm = l & 15, lg = l >> 4;
  int row0 = blockIdx.x * 64 + w * 16;
  const f16* mr = zm + (row0 + lm) * 96;
  const f16* hr = hcur + (row0 + lm) * 96;
  f16x8 am[3], ah[3];
#pragma unroll
  for (int s = 0; s < 3; ++s) {
    am[s] = *(const f16x8*)(mr + s * 32 + lg * 8);
    ah[s] = *(const f16x8*)(hr + s * 32 + lg * 8);
  }
  f32x4 rg[5], zg[5], ni[5], nh[5];
#pragma unroll
  for (int nb = 0; nb < 5; ++nb) {
    int n = nb * 16 + lm;
    float br = 0, bz = 0, bi = 0, bh = 0;
    if (n < 75) {
      br = bih[n] + bhh[n];
      bz = bih[75 + n] + bhh[75 + n];
      bi = bih[150 + n];
      bh = bhh[150 + n];
    }
    rg[nb] = (f32x4){br, br, br, br};
    zg[nb] = (f32x4){bz, bz, bz, bz};
    ni[nb] = (f32x4){bi, bi, bi, bi};
    nh[nb] = (f32x4){bh, bh, bh, bh};
#pragma unroll
    for (int s = 0; s < 3; ++s) {
      int fo = ((nb * 12 + s * 4 + lg) * 16 + lm) * 8;
      rg[nb] = MFMA(am[s], *(const f16x8*)(wihp + fo), rg[nb]);
      rg[nb] = MFMA(ah[s], *(const f16x8*)(whhp + fo), rg[nb]);
      zg[nb] = MFMA(am[s], *(const f16x8*)(wihp + 7680 + fo), zg[nb]);
      zg[nb] = MFMA(ah[s], *(const f16x8*)(whhp + 7680 + fo), zg[nb]);
      ni[nb] = MFMA(am[s], *(const f16x8*)(wihp + 15360 + fo), ni[nb]);
      nh[nb] = MFMA(ah[s], *(const f16x8*)(whhp + 15360 + fo), nh[nb]);
    }
  }
#pragma unroll
  for (int nb = 0; nb < 5; ++nb)
#pragma unroll
    for (int r = 0; r < 4; ++r) {
      int n = nb * 16 + lm;
      int grow = row0 + lg * 4 + r;
      float hval = (float)hcur[grow * 96 + n];
      float rv = 1.f / (1.f + __expf(-rg[nb][r]));
      float zv = 1.f / (1.f + __expf(-zg[nb][r]));
      float nv = tanhf(ni[nb][r] + rv * nh[nb][r]);
      float hp = (1.f - zv) * nv + zv * hval;
      if (xnext) xnext[grow * 96 + n] = (f16)hp;
      if (n < 75) {
        catb[grow * 256 + itoff + n] = (f16)hp;
        if (outx && grow < NN) outx[grow * 75 + n] = hp;
      }
    }
}

// ---------------- readout ----------------

__global__ __launch_bounds__(256) void read1_kernel(const f16* __restrict__ catb,
                                                    const f16* __restrict__ wc1p,
                                                    const float* __restrict__ bc1,
                                                    f16* __restrict__ r1b) {
  int tid = threadIdx.x;
  int w = tid >> 6, l = tid & 63, lm = l & 15, lg = l >> 4;
  int row0 = blockIdx.x * 64 + w * 16;
  const f16* ar = catb + (row0 + lm) * 256;
  f16x8 a[8];
#pragma unroll
  for (int s = 0; s < 8; ++s) a[s] = *(const f16x8*)(ar + s * 32 + lg * 8);
  f32x4 acc[10];
#pragma unroll
  for (int nb = 0; nb < 10; ++nb) {
    int n = nb * 16 + lm;
    float bv = (n < 150) ? bc1[n] : 0.f;
    acc[nb] = (f32x4){bv, bv, bv, bv};
#pragma unroll
    for (int s = 0; s < 8; ++s)
      acc[nb] = MFMA(a[s], *(const f16x8*)(wc1p + ((nb * 32 + s * 4 + lg) * 16 + lm) * 8),
                     acc[nb]);
  }
  f16* orow = r1b + row0 * 160;
#pragma unroll
  for (int nb = 0; nb < 10; ++nb)
#pragma unroll
    for (int r = 0; r < 4; ++r)
      orow[(lg * 4 + r) * 160 + nb * 16 + lm] = (f16)fmaxf(acc[nb][r], 0.f);
}

__global__ __launch_bounds__(256) void read2_kernel(const f16* __restrict__ r1b,
                                                    const f16* __restrict__ wc2p,
                                                    const float* __restrict__ bc2,
                                                    float* __restrict__ out) {
  int tid = threadIdx.x;
  int w = tid >> 6, l = tid & 63, lm = l & 15, lg = l >> 4;
  int row0 = blockIdx.x * 64 + w * 16;
  const f16* ar = r1b + (row0 + lm) * 160;
  f16x8 a[5];
#pragma unroll
  for (int s = 0; s < 5; ++s) a[s] = *(const f16x8*)(ar + s * 32 + lg * 8);
  f32x4 acc[5];
#pragma unroll
  for (int nb = 0; nb < 5; ++nb) {
    int n = nb * 16 + lm;
    float bv = (n < 75) ? bc2[n] : 0.f;
    acc[nb] = (f32x4){bv, bv, bv, bv};
#pragma unroll
    for (int s = 0; s < 5; ++s)
      acc[nb] = MFMA(a[s], *(const f16x8*)(wc2p + ((nb * 20 + s * 4 + lg) * 16 + lm) * 8),
                     acc[nb]);
  }
#pragma unroll
  for (int nb = 0; nb < 5; ++nb)
#pragma unroll
    for (int r = 0; r < 4; ++r) {
      int n = nb * 16 + lm;
      int grow = row0 + lg * 4 + r;
      if (n < 75 && grow < NN) out[grow * 75 + n] = acc[nb][r];
    }
}

// ---------------- launch ----------------

extern "C" void kernel_launch(void* const* d_in, const int* in_sizes, int n_in,
                              void* d_out, int out_size, void* d_ws, size_t ws_size,
                              hipStream_t stream) {
  const float* x    = (const float*)d_in[0];
  const int*   ei   = (const int*)d_in[1];
  const float* eps  = (const float*)d_in[2];
  const float* w1   = (const float*)d_in[3];
  const float* b1   = (const float*)d_in[4];
  const float* w2   = (const float*)d_in[5];
  const float* b2   = (const float*)d_in[6];
  const float* w_ih = (const float*)d_in[7];
  const float* w_hh = (const float*)d_in[8];
  const float* b_ih = (const float*)d_in[9];
  const float* b_hh = (const float*)d_in[10];
  const float* wc1  = (const float*)d_in[11];
  const float* bc1  = (const float*)d_in[12];
  const float* wc2  = (const float*)d_in[13];
  const float* bc2  = (const float*)d_in[14];

  const int* srcv = ei;
  const int* dstv = ei + EE;

  float* out_x = (float*)d_out;              // N*75 final node states (fp32)
  float* out_r = out_x + NN * 75;            // N*75 readout (fp32)

  f16* zm   = (f16*)d_ws;                    // N2*96
  f16* xpB  = zm + (size_t)N2 * 96;          // N2*96
  f16* xpA  = xpB + (size_t)N2 * 96;         // N2*96
  f16* catb = xpA + (size_t)N2 * 96;         // N2*256
  f16* wp   = catb + (size_t)N2 * 256;       // packed weights, 115200 f16
  f16* w1p  = wp;
  f16* w2p  = wp + 7680;
  f16* wihp = wp + 15360;                    // 3 gates x 7680
  f16* whhp = wp + 38400;
  f16* wc1p = wp + 61440;                    // 40960
  f16* wc2p = wp + 102400;                   // 12800
  u32* ebuf = (u32*)(wp + 115200);           // EE
  int* csr  = (int*)(ebuf + EE);             // EE
  int* rsv  = csr + EE;                      // NN+1
  int* bbase = rsv + NN + 1;                 // NBUCK+1
  int* bcur  = bbase + NBUCK + 1;            // NBUCK
  int* bcnt  = bcur + NBUCK;                 // NBUCK
  f16* r1b  = zm;                            // N2*160, aliases zm+xpB (both dead by then)

  hipMemsetAsync(bcnt, 0, NBUCK * sizeof(int), stream);
  bhist_kernel<<<512, 256, 0, stream>>>(dstv, bcnt);
  bscan_kernel<<<1, 1024, 0, stream>>>(bcnt, bbase, bcur, rsv);
  binB_kernel<<<(EE + 255) / 256, 256, 0, stream>>>(srcv, dstv, bcur, ebuf);
  binC_kernel<<<NBUCK, 256, 0, stream>>>(ebuf, bbase, rsv, csr);
  convx_kernel<<<(N2 * 96 + 255) / 256, 256, 0, stream>>>(x, xpA);

  // weight packs
  pack_kernel<<<30, 256, 0, stream>>>(w1, 75, 75, 12, 5, 0, w1p);
  pack_kernel<<<30, 256, 0, stream>>>(w2, 75, 75, 12, 5, 0, w2p);
  for (int g = 0; g < 3; ++g) {
    pack_kernel<<<30, 256, 0, stream>>>(w_ih + g * 5625, 75, 75, 12, 5, 1, wihp + g * 7680);
    pack_kernel<<<30, 256, 0, stream>>>(w_hh + g * 5625, 75, 75, 12, 5, 1, whhp + g * 7680);
  }
  pack_kernel<<<160, 256, 0, stream>>>(wc1, 225, 150, 32, 10, 0, wc1p);
  pack_kernel<<<50, 256, 0, stream>>>(wc2, 150, 75, 20, 5, 0, wc2p);

  int gb = N2 / 64;  // 1563
  for (int it = 0; it < 3; ++it) {
    const f16* h = (it == 1) ? xpB : xpA;
    f16* hn = (it == 0) ? xpB : (it == 1) ? xpA : nullptr;
    aggz_kernel<<<25000, 256, 0, stream>>>(h, rsv, csr, eps, zm);
    mlp_kernel<<<gb, 256, 0, stream>>>(zm, w1p, w2p, b1, b2);
    gru_kernel<<<gb, 256, 0, stream>>>(zm, h, wihp, whhp, b_ih, b_hh, hn, catb, it * 75,
                                       (it == 2) ? out_x : nullptr);
  }
  read1_kernel<<<gb, 256, 0, stream>>>(catb, wc1p, bc1, r1b);
  read2_kernel<<<gb, 256, 0, stream>>>(r1b, wc2p, bc2, out_r);
}

// Round 5
// 757.855 us; speedup vs baseline: 1.8741x; 1.8741x over previous
//
#include <hip/hip_runtime.h>

#define NN 100000
#define EE 3200000
#define N2 100032   // NN rounded up to 64
#define NBUCK 782   // ceil(NN/128)
#define CPAD 16     // counter padding (one per 64B line)
#define CHUNK 4096  // edges per binB block

typedef _Float16 f16;
typedef _Float16 f16x8 __attribute__((ext_vector_type(8)));
typedef float f32x4 __attribute__((ext_vector_type(4)));
typedef unsigned int u32;

#define MFMA(a, b, c) __builtin_amdgcn_mfma_f32_16x16x32_f16((a), (b), (c), 0, 0, 0)

// ---------------- CSR build (binned two-phase, contention-free) ----------------

__global__ __launch_bounds__(256) void bhist_kernel(const int* __restrict__ dst,
                                                    int* __restrict__ bcnt) {
  __shared__ int h[NBUCK];
  int tid = threadIdx.x;
  for (int i = tid; i < NBUCK; i += 256) h[i] = 0;
  __syncthreads();
  for (int e = blockIdx.x * 256 + tid; e < EE; e += gridDim.x * 256)
    atomicAdd(&h[dst[e] >> 7], 1);
  __syncthreads();
  for (int i = tid; i < NBUCK; i += 256) {
    int v = h[i];
    if (v) atomicAdd(&bcnt[i * CPAD], v);
  }
}

__global__ __launch_bounds__(1024) void bscan_kernel(const int* __restrict__ bcnt,
                                                     int* __restrict__ bbase,
                                                     int* __restrict__ bcur,
                                                     int* __restrict__ rs) {
  __shared__ int sb[1024];
  int tid = threadIdx.x;
  int c = (tid < NBUCK) ? bcnt[tid * CPAD] : 0;
  int v = c;
  sb[tid] = v;
  __syncthreads();
  for (int off = 1; off < 1024; off <<= 1) {
    int t = (tid >= off) ? sb[tid - off] : 0;
    __syncthreads();
    v += t;
    sb[tid] = v;
    __syncthreads();
  }
  if (tid < NBUCK) {
    bbase[tid] = v - c;
    bcur[tid * CPAD] = v - c;
  }
  if (tid == 0) {
    bbase[NBUCK] = EE;
    rs[NN] = EE;
  }
}

__global__ __launch_bounds__(256) void binB_kernel(const int* __restrict__ src,
                                                   const int* __restrict__ dst,
                                                   int* __restrict__ bcur,
                                                   u32* __restrict__ ebuf) {
  __shared__ int hist[NBUCK];
  __shared__ int base[NBUCK];
  int tid = threadIdx.x;
  int e0 = blockIdx.x * CHUNK;
  int e1 = e0 + CHUNK;
  if (e1 > EE) e1 = EE;
  for (int i = tid; i < NBUCK; i += 256) hist[i] = 0;
  __syncthreads();
  for (int e = e0 + tid; e < e1; e += 256) atomicAdd(&hist[dst[e] >> 7], 1);
  __syncthreads();
  for (int i = tid; i < NBUCK; i += 256) {
    int c = hist[i];
    if (c) base[i] = atomicAdd(&bcur[i * CPAD], c);
  }
  __syncthreads();
  for (int i = tid; i < NBUCK; i += 256) hist[i] = 0;
  __syncthreads();
  for (int e = e0 + tid; e < e1; e += 256) {
    int d = dst[e];
    int b = d >> 7;
    int loc = atomicAdd(&hist[b], 1);
    ebuf[base[b] + loc] = (u32)src[e] | ((u32)(d & 127) << 17);
  }
}

__global__ __launch_bounds__(256) void binC_kernel(const u32* __restrict__ ebuf,
                                                   const int* __restrict__ bbase,
                                                   int* __restrict__ rs,
                                                   int* __restrict__ csr) {
  __shared__ int cnt[128], sc[128], cur[128];
  int b = blockIdx.x, tid = threadIdx.x;
  int e0 = bbase[b], e1 = bbase[b + 1];
  if (tid < 128) cnt[tid] = 0;
  __syncthreads();
  for (int e = e0 + tid; e < e1; e += 256) atomicAdd(&cnt[ebuf[e] >> 17], 1);
  __syncthreads();
  if (tid < 128) sc[tid] = cnt[tid];
  __syncthreads();
  for (int off = 1; off < 128; off <<= 1) {
    int t = 0;
    if (tid < 128 && tid >= off) t = sc[tid - off];
    __syncthreads();
    if (tid < 128) sc[tid] += t;
    __syncthreads();
  }
  if (tid < 128) {
    int gpos = e0 + sc[tid] - cnt[tid];
    int node = b * 128 + tid;
    if (node < NN) rs[node] = gpos;
    cur[tid] = gpos;
  }
  __syncthreads();
  for (int e = e0 + tid; e < e1; e += 256) {
    u32 p = ebuf[e];
    int pos = atomicAdd(&cur[p >> 17], 1);
    csr[pos] = (int)(p & 0x1FFFFu);
  }
}

// ---------------- weight pack into B-fragment order ----------------

__global__ __launch_bounds__(256) void pack_kernel(const float* __restrict__ W, int K, int Nc,
                                                   int KG, int NB, int trans,
                                                   f16* __restrict__ dst) {
  int i = blockIdx.x * 256 + threadIdx.x;
  if (i >= NB * KG * 128) return;
  int e = i & 7, nn = (i >> 3) & 15;
  int g = (i >> 7) % KG, nb = (i >> 7) / KG;
  int k = g * 8 + e, n = nb * 16 + nn;
  float v = 0.f;
  if (k < K && n < Nc) v = trans ? W[n * K + k] : W[k * Nc + n];
  dst[i] = (f16)v;
}

// ---------------- x -> padded f16 ----------------

__global__ __launch_bounds__(256) void convx_kernel(const float* __restrict__ x,
                                                    f16* __restrict__ xp) {
  int i = blockIdx.x * 256 + threadIdx.x;
  if (i >= N2 * 96) return;
  int r = i / 96, c = i - r * 96;
  xp[i] = (f16)((r < NN && c < 75) ? x[r * 75 + c] : 0.f);
}

// ---------------- aggregation: wave per node, 10 lanes x 16B, 6 edges in flight ----------------

__global__ __launch_bounds__(256) void aggz_kernel(const f16* __restrict__ xc,
                                                   const int* __restrict__ rs,
                                                   const int* __restrict__ csr,
                                                   const float* __restrict__ eps,
                                                   f16* __restrict__ zm) {
  int tid = threadIdx.x;
  int l = tid & 63;
  int n = blockIdx.x * 4 + (tid >> 6);
  if (n >= NN) return;
  int s = l / 10, j = l - s * 10;
  int e0 = rs[n], e1 = rs[n + 1];
  float acc[8] = {0, 0, 0, 0, 0, 0, 0, 0};
  if (l < 60) {
#pragma unroll 2
    for (int e = e0 + s; e < e1; e += 6) {
      int sr = csr[e];
      f16x8 v = *(const f16x8*)(xc + sr * 96 + j * 8);
#pragma unroll
      for (int k = 0; k < 8; ++k) acc[k] += (float)v[k];
    }
  }
  int l1 = (l + 30) & 63, l2 = (l + 10) & 63, l3 = (l + 20) & 63;
#pragma unroll
  for (int k = 0; k < 8; ++k) {
    float t = __shfl(acc[k], l1, 64);
    if (l < 30) acc[k] += t;              // s0..2 += s3..5
    t = __shfl(acc[k], l2, 64);
    if (l < 10) acc[k] += t;              // s0 += s1
    t = __shfl(acc[k], l3, 64);
    if (l < 10) acc[k] += t;              // s0 += s2
  }
  if (l < 10) {
    f16x8 self = *(const f16x8*)(xc + n * 96 + j * 8);
    float ep = 1.f + eps[0];
    f16x8 o;
#pragma unroll
    for (int k = 0; k < 8; ++k) o[k] = (f16)(ep * (float)self[k] + acc[k]);
    *(f16x8*)(zm + n * 96 + j * 8) = o;
  }
}

// ---------------- fused GIN MLP (in-place zm: z -> m), MFMA ----------------

__global__ __launch_bounds__(256) void mlp_kernel(f16* __restrict__ zm,
                                                  const f16* __restrict__ w1p,
                                                  const f16* __restrict__ w2p,
                                                  const float* __restrict__ b1,
                                                  const float* __restrict__ b2) {
  __shared__ f16 m1lds[4][16 * 104];
  int tid = threadIdx.x;
  int w = tid >> 6, l = tid & 63, lm = l & 15, lg = l >> 4;
  int row = blockIdx.x * 64 + w * 16 + lm;
  const f16* ar = zm + row * 96;
  f16x8 a0 = *(const f16x8*)(ar + lg * 8);
  f16x8 a1 = *(const f16x8*)(ar + 32 + lg * 8);
  f16x8 a2 = *(const f16x8*)(ar + 64 + lg * 8);
  f32x4 acc[5];
#pragma unroll
  for (int nb = 0; nb < 5; ++nb) {
    int n = nb * 16 + lm;
    float bv = (n < 75) ? b1[n] : 0.f;
    acc[nb] = (f32x4){bv, bv, bv, bv};
    const f16* bp = w1p + ((nb * 12 + lg) * 16 + lm) * 8;
    acc[nb] = MFMA(a0, *(const f16x8*)bp, acc[nb]);
    acc[nb] = MFMA(a1, *(const f16x8*)(bp + 512), acc[nb]);
    acc[nb] = MFMA(a2, *(const f16x8*)(bp + 1024), acc[nb]);
  }
  f16* Ld = m1lds[w];
#pragma unroll
  for (int nb = 0; nb < 5; ++nb)
#pragma unroll
    for (int r = 0; r < 4; ++r)
      Ld[(lg * 4 + r) * 104 + nb * 16 + lm] = (f16)fmaxf(acc[nb][r], 0.f);
#pragma unroll
  for (int c = 0; c < 4; ++c) Ld[lm * 104 + 80 + lg * 4 + c] = (f16)0.f;  // zero cols 80..95
  __syncthreads();
  const f16* Lr = m1lds[w] + lm * 104;
  f16x8 c0 = *(const f16x8*)(Lr + lg * 8);
  f16x8 c1 = *(const f16x8*)(Lr + 32 + lg * 8);
  f16x8 c2 = *(const f16x8*)(Lr + 64 + lg * 8);
  f32x4 acc2[5];
#pragma unroll
  for (int nb = 0; nb < 5; ++nb) {
    int n = nb * 16 + lm;
    float bv = (n < 75) ? b2[n] : 0.f;
    acc2[nb] = (f32x4){bv, bv, bv, bv};
    const f16* bp = w2p + ((nb * 12 + lg) * 16 + lm) * 8;
    acc2[nb] = MFMA(c0, *(const f16x8*)bp, acc2[nb]);
    acc2[nb] = MFMA(c1, *(const f16x8*)(bp + 512), acc2[nb]);
    acc2[nb] = MFMA(c2, *(const f16x8*)(bp + 1024), acc2[nb]);
  }
  f16* orow = zm + (blockIdx.x * 64 + w * 16) * 96;
#pragma unroll
  for (int nb = 0; nb < 5; ++nb)
#pragma unroll
    for (int r = 0; r < 4; ++r)
      orow[(lg * 4 + r) * 96 + nb * 16 + lm] = (f16)fmaxf(acc2[nb][r], 0.f);
}

// ---------------- GRU step, MFMA ----------------

__global__ __launch_bounds__(256) void gru_kernel(const f16* __restrict__ zm,
                                                  const f16* __restrict__ hcur,
                                                  const f16* __restrict__ wihp,
                                                  const f16* __restrict__ whhp,
                                                  const float* __restrict__ bih,
                                                  const float* __restrict__ bhh,
                                                  f16* __restrict__ xnext,
                                                  f16* __restrict__ catb, int itoff,
                                                  float* __restrict__ outx) {
  int tid = threadIdx.x;
  int w = tid >> 6, l = tid & 63, lm = l & 15, lg = l >> 4;
  int row0 = blockIdx.x * 64 + w * 16;
  const f16* mr = zm + (row0 + lm) * 96;
  const f16* hr = hcur + (row0 + lm) * 96;
  f16x8 am[3], ah[3];
#pragma unroll
  for (int s = 0; s < 3; ++s) {
    am[s] = *(const f16x8*)(mr + s * 32 + lg * 8);
    ah[s] = *(const f16x8*)(hr + s * 32 + lg * 8);
  }
  f32x4 rg[5], zg[5], ni[5], nh[5];
#pragma unroll
  for (int nb = 0; nb < 5; ++nb) {
    int n = nb * 16 + lm;
    float br = 0, bz = 0, bi = 0, bh = 0;
    if (n < 75) {
      br = bih[n] + bhh[n];
      bz = bih[75 + n] + bhh[75 + n];
      bi = bih[150 + n];
      bh = bhh[150 + n];
    }
    rg[nb] = (f32x4){br, br, br, br};
    zg[nb] = (f32x4){bz, bz, bz, bz};
    ni[nb] = (f32x4){bi, bi, bi, bi};
    nh[nb] = (f32x4){bh, bh, bh, bh};
#pragma unroll
    for (int s = 0; s < 3; ++s) {
      int fo = ((nb * 12 + s * 4 + lg) * 16 + lm) * 8;
      rg[nb] = MFMA(am[s], *(const f16x8*)(wihp + fo), rg[nb]);
      rg[nb] = MFMA(ah[s], *(const f16x8*)(whhp + fo), rg[nb]);
      zg[nb] = MFMA(am[s], *(const f16x8*)(wihp + 7680 + fo), zg[nb]);
      zg[nb] = MFMA(ah[s], *(const f16x8*)(whhp + 7680 + fo), zg[nb]);
      ni[nb] = MFMA(am[s], *(const f16x8*)(wihp + 15360 + fo), ni[nb]);
      nh[nb] = MFMA(ah[s], *(const f16x8*)(whhp + 15360 + fo), nh[nb]);
    }
  }
#pragma unroll
  for (int nb = 0; nb < 5; ++nb)
#pragma unroll
    for (int r = 0; r < 4; ++r) {
      int n = nb * 16 + lm;
      int grow = row0 + lg * 4 + r;
      float hval = (float)hcur[grow * 96 + n];
      float rv = 1.f / (1.f + __expf(-rg[nb][r]));
      float zv = 1.f / (1.f + __expf(-zg[nb][r]));
      float nv = tanhf(ni[nb][r] + rv * nh[nb][r]);
      float hp = (1.f - zv) * nv + zv * hval;
      if (xnext) xnext[grow * 96 + n] = (f16)hp;
      if (n < 75) {
        catb[grow * 256 + itoff + n] = (f16)hp;
        if (outx && grow < NN) outx[grow * 75 + n] = hp;
      }
    }
}

// ---------------- readout ----------------

__global__ __launch_bounds__(256) void read1_kernel(const f16* __restrict__ catb,
                                                    const f16* __restrict__ wc1p,
                                                    const float* __restrict__ bc1,
                                                    f16* __restrict__ r1b) {
  int tid = threadIdx.x;
  int w = tid >> 6, l = tid & 63, lm = l & 15, lg = l >> 4;
  int row0 = blockIdx.x * 64 + w * 16;
  const f16* ar = catb + (row0 + lm) * 256;
  f16x8 a[8];
#pragma unroll
  for (int s = 0; s < 8; ++s) a[s] = *(const f16x8*)(ar + s * 32 + lg * 8);
  f32x4 acc[10];
#pragma unroll
  for (int nb = 0; nb < 10; ++nb) {
    int n = nb * 16 + lm;
    float bv = (n < 150) ? bc1[n] : 0.f;
    acc[nb] = (f32x4){bv, bv, bv, bv};
#pragma unroll
    for (int s = 0; s < 8; ++s)
      acc[nb] = MFMA(a[s], *(const f16x8*)(wc1p + ((nb * 32 + s * 4 + lg) * 16 + lm) * 8),
                     acc[nb]);
  }
  f16* orow = r1b + row0 * 160;
#pragma unroll
  for (int nb = 0; nb < 10; ++nb)
#pragma unroll
    for (int r = 0; r < 4; ++r)
      orow[(lg * 4 + r) * 160 + nb * 16 + lm] = (f16)fmaxf(acc[nb][r], 0.f);
}

__global__ __launch_bounds__(256) void read2_kernel(const f16* __restrict__ r1b,
                                                    const f16* __restrict__ wc2p,
                                                    const float* __restrict__ bc2,
                                                    float* __restrict__ out) {
  int tid = threadIdx.x;
  int w = tid >> 6, l = tid & 63, lm = l & 15, lg = l >> 4;
  int row0 = blockIdx.x * 64 + w * 16;
  const f16* ar = r1b + (row0 + lm) * 160;
  f16x8 a[5];
#pragma unroll
  for (int s = 0; s < 5; ++s) a[s] = *(const f16x8*)(ar + s * 32 + lg * 8);
  f32x4 acc[5];
#pragma unroll
  for (int nb = 0; nb < 5; ++nb) {
    int n = nb * 16 + lm;
    float bv = (n < 75) ? bc2[n] : 0.f;
    acc[nb] = (f32x4){bv, bv, bv, bv};
#pragma unroll
    for (int s = 0; s < 5; ++s)
      acc[nb] = MFMA(a[s], *(const f16x8*)(wc2p + ((nb * 20 + s * 4 + lg) * 16 + lm) * 8),
                     acc[nb]);
  }
#pragma unroll
  for (int nb = 0; nb < 5; ++nb)
#pragma unroll
    for (int r = 0; r < 4; ++r) {
      int n = nb * 16 + lm;
      int grow = row0 + lg * 4 + r;
      if (n < 75 && grow < NN) out[grow * 75 + n] = acc[nb][r];
    }
}

// ---------------- launch ----------------

extern "C" void kernel_launch(void* const* d_in, const int* in_sizes, int n_in,
                              void* d_out, int out_size, void* d_ws, size_t ws_size,
                              hipStream_t stream) {
  const float* x    = (const float*)d_in[0];
  const int*   ei   = (const int*)d_in[1];
  const float* eps  = (const float*)d_in[2];
  const float* w1   = (const float*)d_in[3];
  const float* b1   = (const float*)d_in[4];
  const float* w2   = (const float*)d_in[5];
  const float* b2   = (const float*)d_in[6];
  const float* w_ih = (const float*)d_in[7];
  const float* w_hh = (const float*)d_in[8];
  const float* b_ih = (const float*)d_in[9];
  const float* b_hh = (const float*)d_in[10];
  const float* wc1  = (const float*)d_in[11];
  const float* bc1  = (const float*)d_in[12];
  const float* wc2  = (const float*)d_in[13];
  const float* bc2  = (const float*)d_in[14];

  const int* srcv = ei;
  const int* dstv = ei + EE;

  float* out_x = (float*)d_out;              // N*75 final node states (fp32)
  float* out_r = out_x + NN * 75;            // N*75 readout (fp32)

  f16* zm   = (f16*)d_ws;                    // N2*96
  f16* xpB  = zm + (size_t)N2 * 96;          // N2*96
  f16* xpA  = xpB + (size_t)N2 * 96;         // N2*96
  f16* catb = xpA + (size_t)N2 * 96;         // N2*256
  f16* wp   = catb + (size_t)N2 * 256;       // packed weights, 115200 f16
  f16* w1p  = wp;
  f16* w2p  = wp + 7680;
  f16* wihp = wp + 15360;                    // 3 gates x 7680
  f16* whhp = wp + 38400;
  f16* wc1p = wp + 61440;                    // 40960
  f16* wc2p = wp + 102400;                   // 12800
  u32* ebuf = (u32*)(wp + 115200);           // EE
  int* csr  = (int*)(ebuf + EE);             // EE
  int* rsv  = csr + EE;                      // NN+1
  int* bbase = rsv + NN + 1;                 // NBUCK+1
  int* bcur  = bbase + NBUCK + 1;            // NBUCK*CPAD
  int* bcnt  = bcur + NBUCK * CPAD;          // NBUCK*CPAD
  f16* r1b  = zm;                            // N2*160, aliases zm+xpB (both dead by then)

  hipMemsetAsync(bcnt, 0, NBUCK * CPAD * sizeof(int), stream);
  bhist_kernel<<<512, 256, 0, stream>>>(dstv, bcnt);
  bscan_kernel<<<1, 1024, 0, stream>>>(bcnt, bbase, bcur, rsv);
  binB_kernel<<<(EE + CHUNK - 1) / CHUNK, 256, 0, stream>>>(srcv, dstv, bcur, ebuf);
  binC_kernel<<<NBUCK, 256, 0, stream>>>(ebuf, bbase, rsv, csr);
  convx_kernel<<<(N2 * 96 + 255) / 256, 256, 0, stream>>>(x, xpA);

  // weight packs
  pack_kernel<<<30, 256, 0, stream>>>(w1, 75, 75, 12, 5, 0, w1p);
  pack_kernel<<<30, 256, 0, stream>>>(w2, 75, 75, 12, 5, 0, w2p);
  for (int g = 0; g < 3; ++g) {
    pack_kernel<<<30, 256, 0, stream>>>(w_ih + g * 5625, 75, 75, 12, 5, 1, wihp + g * 7680);
    pack_kernel<<<30, 256, 0, stream>>>(w_hh + g * 5625, 75, 75, 12, 5, 1, whhp + g * 7680);
  }
  pack_kernel<<<160, 256, 0, stream>>>(wc1, 225, 150, 32, 10, 0, wc1p);
  pack_kernel<<<50, 256, 0, stream>>>(wc2, 150, 75, 20, 5, 0, wc2p);

  int gb = N2 / 64;  // 1563
  for (int it = 0; it < 3; ++it) {
    const f16* h = (it == 1) ? xpB : xpA;
    f16* hn = (it == 0) ? xpB : (it == 1) ? xpA : nullptr;
    aggz_kernel<<<25000, 256, 0, stream>>>(h, rsv, csr, eps, zm);
    mlp_kernel<<<gb, 256, 0, stream>>>(zm, w1p, w2p, b1, b2);
    gru_kernel<<<gb, 256, 0, stream>>>(zm, h, wihp, whhp, b_ih, b_hh, hn, catb, it * 75,
                                       (it == 2) ? out_x : nullptr);
  }
  read1_kernel<<<gb, 256, 0, stream>>>(catb, wc1p, bc1, r1b);
  read2_kernel<<<gb, 256, 0, stream>>>(r1b, wc2p, bc2, out_r);
}

// Round 6
// 750.478 us; speedup vs baseline: 1.8925x; 1.0098x over previous
//
#include <hip/hip_runtime.h>

#define NN 100000
#define EE 3200000
#define N2 100032   // NN rounded up to 64
#define NBUCK 782   // ceil(NN/128)
#define CPAD 16     // counter padding (one per 64B line)
#define CHUNK 12288 // edges per binB block (div by 4; EE%4==0 so no ragged tail)

typedef _Float16 f16;
typedef _Float16 f16x8 __attribute__((ext_vector_type(8)));
typedef float f32x4 __attribute__((ext_vector_type(4)));
typedef unsigned int u32;

#define MFMA(a, b, c) __builtin_amdgcn_mfma_f32_16x16x32_f16((a), (b), (c), 0, 0, 0)

// ---------------- CSR build (binned two-phase, contention-free) ----------------

__global__ __launch_bounds__(256) void bhist_kernel(const int4* __restrict__ dst4,
                                                    int* __restrict__ bcnt) {
  __shared__ int h[2][NBUCK];
  int tid = threadIdx.x;
  for (int i = tid; i < 2 * NBUCK; i += 256) ((int*)h)[i] = 0;
  __syncthreads();
  int r = (tid >> 7) & 1;
  for (int i = blockIdx.x * 256 + tid; i < EE / 4; i += gridDim.x * 256) {
    int4 d = dst4[i];
    atomicAdd(&h[r][d.x >> 7], 1);
    atomicAdd(&h[r][d.y >> 7], 1);
    atomicAdd(&h[r][d.z >> 7], 1);
    atomicAdd(&h[r][d.w >> 7], 1);
  }
  __syncthreads();
  for (int i = tid; i < NBUCK; i += 256) {
    int v = h[0][i] + h[1][i];
    if (v) atomicAdd(&bcnt[i * CPAD], v);
  }
}

__global__ __launch_bounds__(1024) void bscan_kernel(const int* __restrict__ bcnt,
                                                     int* __restrict__ bbase,
                                                     int* __restrict__ bcur,
                                                     int* __restrict__ rs) {
  __shared__ int sb[1024];
  int tid = threadIdx.x;
  int c = (tid < NBUCK) ? bcnt[tid * CPAD] : 0;
  int v = c;
  sb[tid] = v;
  __syncthreads();
  for (int off = 1; off < 1024; off <<= 1) {
    int t = (tid >= off) ? sb[tid - off] : 0;
    __syncthreads();
    v += t;
    sb[tid] = v;
    __syncthreads();
  }
  if (tid < NBUCK) {
    bbase[tid] = v - c;
    bcur[tid * CPAD] = v - c;
  }
  if (tid == 0) {
    bbase[NBUCK] = EE;
    rs[NN] = EE;
  }
}

__global__ __launch_bounds__(256) void binB_kernel(const int* __restrict__ src,
                                                   const int* __restrict__ dst,
                                                   int* __restrict__ bcur,
                                                   u32* __restrict__ ebuf) {
  __shared__ int hist[NBUCK];
  __shared__ int base[NBUCK];
  int tid = threadIdx.x;
  int e0 = blockIdx.x * CHUNK;
  int e1 = e0 + CHUNK;
  if (e1 > EE) e1 = EE;
  for (int i = tid; i < NBUCK; i += 256) hist[i] = 0;
  __syncthreads();
  for (int e = e0 + tid * 4; e < e1; e += 1024) {
    int4 d = *(const int4*)(dst + e);
    atomicAdd(&hist[d.x >> 7], 1);
    atomicAdd(&hist[d.y >> 7], 1);
    atomicAdd(&hist[d.z >> 7], 1);
    atomicAdd(&hist[d.w >> 7], 1);
  }
  __syncthreads();
  for (int i = tid; i < NBUCK; i += 256) {
    int c = hist[i];
    if (c) base[i] = atomicAdd(&bcur[i * CPAD], c);
  }
  __syncthreads();
  for (int i = tid; i < NBUCK; i += 256) hist[i] = 0;
  __syncthreads();
  for (int e = e0 + tid * 4; e < e1; e += 1024) {
    int4 d = *(const int4*)(dst + e);
    int4 s = *(const int4*)(src + e);
    int b, loc;
    b = d.x >> 7; loc = atomicAdd(&hist[b], 1);
    ebuf[base[b] + loc] = (u32)s.x | ((u32)(d.x & 127) << 17);
    b = d.y >> 7; loc = atomicAdd(&hist[b], 1);
    ebuf[base[b] + loc] = (u32)s.y | ((u32)(d.y & 127) << 17);
    b = d.z >> 7; loc = atomicAdd(&hist[b], 1);
    ebuf[base[b] + loc] = (u32)s.z | ((u32)(d.z & 127) << 17);
    b = d.w >> 7; loc = atomicAdd(&hist[b], 1);
    ebuf[base[b] + loc] = (u32)s.w | ((u32)(d.w & 127) << 17);
  }
}

__global__ __launch_bounds__(256) void binC_kernel(const u32* __restrict__ ebuf,
                                                   const int* __restrict__ bbase,
                                                   int* __restrict__ rs,
                                                   int* __restrict__ csr) {
  __shared__ int cnt[128], sc[128], cur[128];
  int b = blockIdx.x, tid = threadIdx.x;
  int e0 = bbase[b], e1 = bbase[b + 1];
  if (tid < 128) cnt[tid] = 0;
  __syncthreads();
  for (int e = e0 + tid; e < e1; e += 256) atomicAdd(&cnt[ebuf[e] >> 17], 1);
  __syncthreads();
  if (tid < 128) sc[tid] = cnt[tid];
  __syncthreads();
  for (int off = 1; off < 128; off <<= 1) {
    int t = 0;
    if (tid < 128 && tid >= off) t = sc[tid - off];
    __syncthreads();
    if (tid < 128) sc[tid] += t;
    __syncthreads();
  }
  if (tid < 128) {
    int gpos = e0 + sc[tid] - cnt[tid];
    int node = b * 128 + tid;
    if (node < NN) rs[node] = gpos;
    cur[tid] = gpos;
  }
  __syncthreads();
  for (int e = e0 + tid; e < e1; e += 256) {
    u32 p = ebuf[e];
    int pos = atomicAdd(&cur[p >> 17], 1);
    csr[pos] = (int)(p & 0x1FFFFu);
  }
}

// ---------------- all weight packs in one kernel (B-fragment order) ----------------
// layout: dst[((nb*KG + g)*16 + nn)*8 + e] = W[k=g*8+e][n=nb*16+nn], zero-padded

__device__ __forceinline__ f16 pack_one(const float* __restrict__ W, int rel, int K, int Nc,
                                        int KG, int trans) {
  int e = rel & 7, nn = (rel >> 3) & 15;
  int g = (rel >> 7) % KG, nb = (rel >> 7) / KG;
  int k = g * 8 + e, n = nb * 16 + nn;
  float v = 0.f;
  if (k < K && n < Nc) v = trans ? W[n * K + k] : W[k * Nc + n];
  return (f16)v;
}

__global__ __launch_bounds__(256) void packall_kernel(const float* __restrict__ w1,
                                                      const float* __restrict__ w2,
                                                      const float* __restrict__ wih,
                                                      const float* __restrict__ whh,
                                                      const float* __restrict__ wc1,
                                                      const float* __restrict__ wc2,
                                                      f16* __restrict__ wp) {
  int i = blockIdx.x * 256 + threadIdx.x;
  if (i >= 115200) return;
  f16 v;
  if (i < 7680) v = pack_one(w1, i, 75, 75, 12, 0);
  else if (i < 15360) v = pack_one(w2, i - 7680, 75, 75, 12, 0);
  else if (i < 38400) {
    int r = i - 15360, g = r / 7680;
    v = pack_one(wih + g * 5625, r - g * 7680, 75, 75, 12, 1);
  } else if (i < 61440) {
    int r = i - 38400, g = r / 7680;
    v = pack_one(whh + g * 5625, r - g * 7680, 75, 75, 12, 1);
  } else if (i < 102400) v = pack_one(wc1, i - 61440, 225, 150, 32, 0);
  else v = pack_one(wc2, i - 102400, 150, 75, 20, 0);
  wp[i] = v;
}

// ---------------- x -> padded f16 ----------------

__global__ __launch_bounds__(256) void convx_kernel(const float* __restrict__ x,
                                                    f16* __restrict__ xp) {
  int i = blockIdx.x * 256 + threadIdx.x;
  if (i >= N2 * 96) return;
  int r = i / 96, c = i - r * 96;
  xp[i] = (f16)((r < NN && c < 75) ? x[r * 75 + c] : 0.f);
}

// ---------------- aggregation: wave per node, 10 lanes x 16B, 6 edges in flight ----------------

__global__ __launch_bounds__(256) void aggz_kernel(const f16* __restrict__ xc,
                                                   const int* __restrict__ rs,
                                                   const int* __restrict__ csr,
                                                   const float* __restrict__ eps,
                                                   f16* __restrict__ zm) {
  int tid = threadIdx.x;
  int l = tid & 63;
  int n = blockIdx.x * 4 + (tid >> 6);
  if (n >= NN) return;
  int s = l / 10, j = l - s * 10;
  int e0 = rs[n], e1 = rs[n + 1];
  float acc[8] = {0, 0, 0, 0, 0, 0, 0, 0};
  if (l < 60) {
#pragma unroll 2
    for (int e = e0 + s; e < e1; e += 6) {
      int sr = csr[e];
      f16x8 v = *(const f16x8*)(xc + sr * 96 + j * 8);
#pragma unroll
      for (int k = 0; k < 8; ++k) acc[k] += (float)v[k];
    }
  }
  int l1 = (l + 30) & 63, l2 = (l + 10) & 63, l3 = (l + 20) & 63;
#pragma unroll
  for (int k = 0; k < 8; ++k) {
    float t = __shfl(acc[k], l1, 64);
    if (l < 30) acc[k] += t;              // s0..2 += s3..5
    t = __shfl(acc[k], l2, 64);
    if (l < 10) acc[k] += t;              // s0 += s1
    t = __shfl(acc[k], l3, 64);
    if (l < 10) acc[k] += t;              // s0 += s2
  }
  if (l < 10) {
    f16x8 self = *(const f16x8*)(xc + n * 96 + j * 8);
    float ep = 1.f + eps[0];
    f16x8 o;
#pragma unroll
    for (int k = 0; k < 8; ++k) o[k] = (f16)(ep * (float)self[k] + acc[k]);
    *(f16x8*)(zm + n * 96 + j * 8) = o;
  }
}

// ---------------- fused GIN-MLP + GRU step (m stays in LDS) ----------------

__global__ __launch_bounds__(256) void mlpgru_kernel(const f16* __restrict__ zm,
                                                     const f16* __restrict__ hcur,
                                                     const f16* __restrict__ w1p,
                                                     const f16* __restrict__ w2p,
                                                     const float* __restrict__ b1,
                                                     const float* __restrict__ b2,
                                                     const f16* __restrict__ wihp,
                                                     const f16* __restrict__ whhp,
                                                     const float* __restrict__ bih,
                                                     const float* __restrict__ bhh,
                                                     f16* __restrict__ xnext,
                                                     f16* __restrict__ catb, int itoff,
                                                     float* __restrict__ outx) {
  __shared__ f16 Ls[4][16 * 104];
  int tid = threadIdx.x;
  int w = tid >> 6, l = tid & 63, lm = l & 15, lg = l >> 4;
  int row0 = blockIdx.x * 64 + w * 16;
  // --- MLP layer 1: A from zm (global), acc = z@w1+b1
  const f16* ar = zm + (row0 + lm) * 96;
  f16x8 a0 = *(const f16x8*)(ar + lg * 8);
  f16x8 a1 = *(const f16x8*)(ar + 32 + lg * 8);
  f16x8 a2 = *(const f16x8*)(ar + 64 + lg * 8);
  f32x4 acc[5];
#pragma unroll
  for (int nb = 0; nb < 5; ++nb) {
    int n = nb * 16 + lm;
    float bv = (n < 75) ? b1[n] : 0.f;
    acc[nb] = (f32x4){bv, bv, bv, bv};
    const f16* bp = w1p + ((nb * 12 + lg) * 16 + lm) * 8;
    acc[nb] = MFMA(a0, *(const f16x8*)bp, acc[nb]);
    acc[nb] = MFMA(a1, *(const f16x8*)(bp + 512), acc[nb]);
    acc[nb] = MFMA(a2, *(const f16x8*)(bp + 1024), acc[nb]);
  }
  f16* Ld = Ls[w];
#pragma unroll
  for (int nb = 0; nb < 5; ++nb)
#pragma unroll
    for (int r = 0; r < 4; ++r)
      Ld[(lg * 4 + r) * 104 + nb * 16 + lm] = (f16)fmaxf(acc[nb][r], 0.f);
#pragma unroll
  for (int c = 0; c < 4; ++c) Ld[lm * 104 + 80 + lg * 4 + c] = (f16)0.f;  // zero cols 80..95
  __syncthreads();
  // --- MLP layer 2
  const f16* Lr = Ls[w] + lm * 104;
  f16x8 c0 = *(const f16x8*)(Lr + lg * 8);
  f16x8 c1 = *(const f16x8*)(Lr + 32 + lg * 8);
  f16x8 c2 = *(const f16x8*)(Lr + 64 + lg * 8);
  f32x4 acc2[5];
#pragma unroll
  for (int nb = 0; nb < 5; ++nb) {
    int n = nb * 16 + lm;
    float bv = (n < 75) ? b2[n] : 0.f;
    acc2[nb] = (f32x4){bv, bv, bv, bv};
    const f16* bp = w2p + ((nb * 12 + lg) * 16 + lm) * 8;
    acc2[nb] = MFMA(c0, *(const f16x8*)bp, acc2[nb]);
    acc2[nb] = MFMA(c1, *(const f16x8*)(bp + 512), acc2[nb]);
    acc2[nb] = MFMA(c2, *(const f16x8*)(bp + 1024), acc2[nb]);
  }
  __syncthreads();
  // --- m = relu(...) back to LDS (cols 80..95 still zero)
#pragma unroll
  for (int nb = 0; nb < 5; ++nb)
#pragma unroll
    for (int r = 0; r < 4; ++r)
      Ld[(lg * 4 + r) * 104 + nb * 16 + lm] = (f16)fmaxf(acc2[nb][r], 0.f);
  __syncthreads();
  // --- GRU: m-frags from LDS, h-frags from global
  const f16* mrow = Ls[w] + lm * 104;
  const f16* hr = hcur + (row0 + lm) * 96;
  f16x8 am[3], ah[3];
#pragma unroll
  for (int s = 0; s < 3; ++s) {
    am[s] = *(const f16x8*)(mrow + s * 32 + lg * 8);
    ah[s] = *(const f16x8*)(hr + s * 32 + lg * 8);
  }
  f32x4 rg[5], zg[5], ni[5], nh[5];
#pragma unroll
  for (int nb = 0; nb < 5; ++nb) {
    int n = nb * 16 + lm;
    float br = 0, bz = 0, bi = 0, bh = 0;
    if (n < 75) {
      br = bih[n] + bhh[n];
      bz = bih[75 + n] + bhh[75 + n];
      bi = bih[150 + n];
      bh = bhh[150 + n];
    }
    rg[nb] = (f32x4){br, br, br, br};
    zg[nb] = (f32x4){bz, bz, bz, bz};
    ni[nb] = (f32x4){bi, bi, bi, bi};
    nh[nb] = (f32x4){bh, bh, bh, bh};
#pragma unroll
    for (int s = 0; s < 3; ++s) {
      int fo = ((nb * 12 + s * 4 + lg) * 16 + lm) * 8;
      rg[nb] = MFMA(am[s], *(const f16x8*)(wihp + fo), rg[nb]);
      rg[nb] = MFMA(ah[s], *(const f16x8*)(whhp + fo), rg[nb]);
      zg[nb] = MFMA(am[s], *(const f16x8*)(wihp + 7680 + fo), zg[nb]);
      zg[nb] = MFMA(ah[s], *(const f16x8*)(whhp + 7680 + fo), zg[nb]);
      ni[nb] = MFMA(am[s], *(const f16x8*)(wihp + 15360 + fo), ni[nb]);
      nh[nb] = MFMA(ah[s], *(const f16x8*)(whhp + 15360 + fo), nh[nb]);
    }
  }
#pragma unroll
  for (int nb = 0; nb < 5; ++nb)
#pragma unroll
    for (int r = 0; r < 4; ++r) {
      int n = nb * 16 + lm;
      int grow = row0 + lg * 4 + r;
      float hval = (float)hcur[grow * 96 + n];
      float rv = 1.f / (1.f + __expf(-rg[nb][r]));
      float zv = 1.f / (1.f + __expf(-zg[nb][r]));
      float nv = tanhf(ni[nb][r] + rv * nh[nb][r]);
      float hp = (1.f - zv) * nv + zv * hval;
      if (xnext) xnext[grow * 96 + n] = (f16)hp;
      if (n < 75) {
        catb[grow * 256 + itoff + n] = (f16)hp;
        if (outx && grow < NN) outx[grow * 75 + n] = hp;
      }
    }
}

// ---------------- fused readout (r1 stays in LDS) ----------------

__global__ __launch_bounds__(256) void readout_kernel(const f16* __restrict__ catb,
                                                      const f16* __restrict__ wc1p,
                                                      const float* __restrict__ bc1,
                                                      const f16* __restrict__ wc2p,
                                                      const float* __restrict__ bc2,
                                                      float* __restrict__ out) {
  __shared__ f16 Ls[4][16 * 168];
  int tid = threadIdx.x;
  int w = tid >> 6, l = tid & 63, lm = l & 15, lg = l >> 4;
  int row0 = blockIdx.x * 64 + w * 16;
  const f16* ar = catb + (row0 + lm) * 256;
  f16x8 a[8];
#pragma unroll
  for (int s = 0; s < 8; ++s) a[s] = *(const f16x8*)(ar + s * 32 + lg * 8);
  f32x4 acc[10];
#pragma unroll
  for (int nb = 0; nb < 10; ++nb) {
    int n = nb * 16 + lm;
    float bv = (n < 150) ? bc1[n] : 0.f;
    acc[nb] = (f32x4){bv, bv, bv, bv};
#pragma unroll
    for (int s = 0; s < 8; ++s)
      acc[nb] = MFMA(a[s], *(const f16x8*)(wc1p + ((nb * 32 + s * 4 + lg) * 16 + lm) * 8),
                     acc[nb]);
  }
  f16* Ld = Ls[w];
#pragma unroll
  for (int nb = 0; nb < 10; ++nb)
#pragma unroll
    for (int r = 0; r < 4; ++r)
      Ld[(lg * 4 + r) * 168 + nb * 16 + lm] = (f16)fmaxf(acc[nb][r], 0.f);
  __syncthreads();
  const f16* Lr = Ls[w] + lm * 168;
  f16x8 a2[5];
#pragma unroll
  for (int s = 0; s < 5; ++s) a2[s] = *(const f16x8*)(Lr + s * 32 + lg * 8);
  f32x4 acc2[5];
#pragma unroll
  for (int nb = 0; nb < 5; ++nb) {
    int n = nb * 16 + lm;
    float bv = (n < 75) ? bc2[n] : 0.f;
    acc2[nb] = (f32x4){bv, bv, bv, bv};
#pragma unroll
    for (int s = 0; s < 5; ++s)
      acc2[nb] = MFMA(a2[s], *(const f16x8*)(wc2p + ((nb * 20 + s * 4 + lg) * 16 + lm) * 8),
                     acc2[nb]);
  }
#pragma unroll
  for (int nb = 0; nb < 5; ++nb)
#pragma unroll
    for (int r = 0; r < 4; ++r) {
      int n = nb * 16 + lm;
      int grow = row0 + lg * 4 + r;
      if (n < 75 && grow < NN) out[grow * 75 + n] = acc2[nb][r];
    }
}

// ---------------- launch ----------------

extern "C" void kernel_launch(void* const* d_in, const int* in_sizes, int n_in,
                              void* d_out, int out_size, void* d_ws, size_t ws_size,
                              hipStream_t stream) {
  const float* x    = (const float*)d_in[0];
  const int*   ei   = (const int*)d_in[1];
  const float* eps  = (const float*)d_in[2];
  const float* w1   = (const float*)d_in[3];
  const float* b1   = (const float*)d_in[4];
  const float* w2   = (const float*)d_in[5];
  const float* b2   = (const float*)d_in[6];
  const float* w_ih = (const float*)d_in[7];
  const float* w_hh = (const float*)d_in[8];
  const float* b_ih = (const float*)d_in[9];
  const float* b_hh = (const float*)d_in[10];
  const float* wc1  = (const float*)d_in[11];
  const float* bc1  = (const float*)d_in[12];
  const float* wc2  = (const float*)d_in[13];
  const float* bc2  = (const float*)d_in[14];

  const int* srcv = ei;
  const int* dstv = ei + EE;

  float* out_x = (float*)d_out;              // N*75 final node states (fp32)
  float* out_r = out_x + NN * 75;            // N*75 readout (fp32)

  f16* zm   = (f16*)d_ws;                    // N2*96
  f16* xpB  = zm + (size_t)N2 * 96;          // N2*96
  f16* xpA  = xpB + (size_t)N2 * 96;         // N2*96
  f16* catb = xpA + (size_t)N2 * 96;         // N2*256
  f16* wp   = catb + (size_t)N2 * 256;       // packed weights, 115200 f16
  f16* w1p  = wp;
  f16* w2p  = wp + 7680;
  f16* wihp = wp + 15360;                    // 3 gates x 7680
  f16* whhp = wp + 38400;
  f16* wc1p = wp + 61440;                    // 40960
  f16* wc2p = wp + 102400;                   // 12800
  u32* ebuf = (u32*)(wp + 115200);           // EE
  int* csr  = (int*)(ebuf + EE);             // EE
  int* rsv  = csr + EE;                      // NN+1
  int* bbase = rsv + NN + 1;                 // NBUCK+1
  int* bcur  = bbase + NBUCK + 1;            // NBUCK*CPAD
  int* bcnt  = bcur + NBUCK * CPAD;          // NBUCK*CPAD

  hipMemsetAsync(bcnt, 0, NBUCK * CPAD * sizeof(int), stream);
  bhist_kernel<<<512, 256, 0, stream>>>((const int4*)dstv, bcnt);
  bscan_kernel<<<1, 1024, 0, stream>>>(bcnt, bbase, bcur, rsv);
  binB_kernel<<<(EE + CHUNK - 1) / CHUNK, 256, 0, stream>>>(srcv, dstv, bcur, ebuf);
  binC_kernel<<<NBUCK, 256, 0, stream>>>(ebuf, bbase, rsv, csr);
  convx_kernel<<<(N2 * 96 + 255) / 256, 256, 0, stream>>>(x, xpA);
  packall_kernel<<<450, 256, 0, stream>>>(w1, w2, w_ih, w_hh, wc1, wc2, wp);

  int gb = N2 / 64;  // 1563
  for (int it = 0; it < 3; ++it) {
    const f16* h = (it == 1) ? xpB : xpA;
    f16* hn = (it == 0) ? xpB : (it == 1) ? xpA : nullptr;
    aggz_kernel<<<25000, 256, 0, stream>>>(h, rsv, csr, eps, zm);
    mlpgru_kernel<<<gb, 256, 0, stream>>>(zm, h, w1p, w2p, b1, b2, wihp, whhp, b_ih, b_hh,
                                          hn, catb, it * 75, (it == 2) ? out_x : nullptr);
  }
  readout_kernel<<<gb, 256, 0, stream>>>(catb, wc1p, bc1, wc2p, bc2, out_r);
}

// Round 7
// 705.124 us; speedup vs baseline: 2.0142x; 1.0643x over previous
//
#include <hip/hip_runtime.h>

#define NN 100000
#define EE 3200000
#define N2 100032   // NN rounded up to 64
#define NBUCK 782   // ceil(NN/128)
#define CPAD 16     // counter padding (one per 64B line)
#define CHUNK 12288 // edges per binB block

typedef _Float16 f16;
typedef _Float16 f16x8 __attribute__((ext_vector_type(8)));
typedef float f32x4 __attribute__((ext_vector_type(4)));
typedef unsigned int u32;

#define MFMA(a, b, c) __builtin_amdgcn_mfma_f32_16x16x32_f16((a), (b), (c), 0, 0, 0)

// ---------------- CSR build (binned two-phase, contention-free) ----------------

__global__ __launch_bounds__(256) void bhist_kernel(const int4* __restrict__ dst4,
                                                    int* __restrict__ bcnt) {
  __shared__ int h[2][NBUCK];
  int tid = threadIdx.x;
  for (int i = tid; i < 2 * NBUCK; i += 256) ((int*)h)[i] = 0;
  __syncthreads();
  int r = (tid >> 7) & 1;
  for (int i = blockIdx.x * 256 + tid; i < EE / 4; i += gridDim.x * 256) {
    int4 d = dst4[i];
    atomicAdd(&h[r][d.x >> 7], 1);
    atomicAdd(&h[r][d.y >> 7], 1);
    atomicAdd(&h[r][d.z >> 7], 1);
    atomicAdd(&h[r][d.w >> 7], 1);
  }
  __syncthreads();
  for (int i = tid; i < NBUCK; i += 256) {
    int v = h[0][i] + h[1][i];
    if (v) atomicAdd(&bcnt[i * CPAD], v);
  }
}

__global__ __launch_bounds__(1024) void bscan_kernel(const int* __restrict__ bcnt,
                                                     int* __restrict__ bbase,
                                                     int* __restrict__ bcur,
                                                     int* __restrict__ rs) {
  __shared__ int sb[1024];
  int tid = threadIdx.x;
  int c = (tid < NBUCK) ? bcnt[tid * CPAD] : 0;
  int v = c;
  sb[tid] = v;
  __syncthreads();
  for (int off = 1; off < 1024; off <<= 1) {
    int t = (tid >= off) ? sb[tid - off] : 0;
    __syncthreads();
    v += t;
    sb[tid] = v;
    __syncthreads();
  }
  if (tid < NBUCK) {
    bbase[tid] = v - c;
    bcur[tid * CPAD] = v - c;
  }
  if (tid == 0) {
    bbase[NBUCK] = EE;
    rs[NN] = EE;
  }
}

__global__ __launch_bounds__(256) void binB_kernel(const int* __restrict__ src,
                                                   const int* __restrict__ dst,
                                                   int* __restrict__ bcur,
                                                   u32* __restrict__ ebuf) {
  __shared__ int hist[NBUCK];
  __shared__ int base[NBUCK];
  int tid = threadIdx.x;
  int e0 = blockIdx.x * CHUNK;
  int e1 = e0 + CHUNK;
  if (e1 > EE) e1 = EE;
  for (int i = tid; i < NBUCK; i += 256) hist[i] = 0;
  __syncthreads();
  for (int e = e0 + tid * 4; e < e1; e += 1024) {
    int4 d = *(const int4*)(dst + e);
    atomicAdd(&hist[d.x >> 7], 1);
    atomicAdd(&hist[d.y >> 7], 1);
    atomicAdd(&hist[d.z >> 7], 1);
    atomicAdd(&hist[d.w >> 7], 1);
  }
  __syncthreads();
  for (int i = tid; i < NBUCK; i += 256) {
    int c = hist[i];
    if (c) base[i] = atomicAdd(&bcur[i * CPAD], c);
  }
  __syncthreads();
  for (int i = tid; i < NBUCK; i += 256) hist[i] = 0;
  __syncthreads();
  for (int e = e0 + tid * 4; e < e1; e += 1024) {
    int4 d = *(const int4*)(dst + e);
    int4 s = *(const int4*)(src + e);
    int b, loc;
    b = d.x >> 7; loc = atomicAdd(&hist[b], 1);
    ebuf[base[b] + loc] = (u32)s.x | ((u32)(d.x & 127) << 17);
    b = d.y >> 7; loc = atomicAdd(&hist[b], 1);
    ebuf[base[b] + loc] = (u32)s.y | ((u32)(d.y & 127) << 17);
    b = d.z >> 7; loc = atomicAdd(&hist[b], 1);
    ebuf[base[b] + loc] = (u32)s.z | ((u32)(d.z & 127) << 17);
    b = d.w >> 7; loc = atomicAdd(&hist[b], 1);
    ebuf[base[b] + loc] = (u32)s.w | ((u32)(d.w & 127) << 17);
  }
}

__global__ __launch_bounds__(256) void binC_kernel(const u32* __restrict__ ebuf,
                                                   const int* __restrict__ bbase,
                                                   int* __restrict__ rs,
                                                   int* __restrict__ csr) {
  __shared__ int cnt[128], sc[128], cur[128];
  int b = blockIdx.x, tid = threadIdx.x;
  int e0 = bbase[b], e1 = bbase[b + 1];
  if (tid < 128) cnt[tid] = 0;
  __syncthreads();
  for (int e = e0 + tid; e < e1; e += 256) atomicAdd(&cnt[ebuf[e] >> 17], 1);
  __syncthreads();
  if (tid < 128) sc[tid] = cnt[tid];
  __syncthreads();
  for (int off = 1; off < 128; off <<= 1) {
    int t = 0;
    if (tid < 128 && tid >= off) t = sc[tid - off];
    __syncthreads();
    if (tid < 128) sc[tid] += t;
    __syncthreads();
  }
  if (tid < 128) {
    int gpos = e0 + sc[tid] - cnt[tid];
    int node = b * 128 + tid;
    if (node < NN) rs[node] = gpos;
    cur[tid] = gpos;
  }
  __syncthreads();
  for (int e = e0 + tid; e < e1; e += 256) {
    u32 p = ebuf[e];
    int pos = atomicAdd(&cur[p >> 17], 1);
    csr[pos] = (int)(p & 0x1FFFFu);
  }
}

// ---------------- all weight packs in one kernel (B-fragment order) ----------------
// layout: dst[((nb*KG + g)*16 + nn)*8 + e] = W[k=g*8+e][n=nb*16+nn], zero-padded

__device__ __forceinline__ f16 pack_one(const float* __restrict__ W, int rel, int K, int Nc,
                                        int KG, int trans) {
  int e = rel & 7, nn = (rel >> 3) & 15;
  int g = (rel >> 7) % KG, nb = (rel >> 7) / KG;
  int k = g * 8 + e, n = nb * 16 + nn;
  float v = 0.f;
  if (k < K && n < Nc) v = trans ? W[n * K + k] : W[k * Nc + n];
  return (f16)v;
}

__global__ __launch_bounds__(256) void packall_kernel(const float* __restrict__ w1,
                                                      const float* __restrict__ w2,
                                                      const float* __restrict__ wih,
                                                      const float* __restrict__ whh,
                                                      const float* __restrict__ wc1,
                                                      const float* __restrict__ wc2,
                                                      f16* __restrict__ wp) {
  int i = blockIdx.x * 256 + threadIdx.x;
  if (i >= 120320) return;
  f16 v;
  if (i < 7680) v = pack_one(w1, i, 75, 75, 12, 0);
  else if (i < 15360) v = pack_one(w2, i - 7680, 75, 75, 12, 0);
  else if (i < 38400) {
    int r = i - 15360, g = r / 7680;
    v = pack_one(wih + g * 5625, r - g * 7680, 75, 75, 12, 1);
  } else if (i < 61440) {
    int r = i - 38400, g = r / 7680;
    v = pack_one(whh + g * 5625, r - g * 7680, 75, 75, 12, 1);
  } else if (i < 107520) {
    // wc1 remap: 288 k-slots = 3 x (75 valid + 21 zero-pad)
    int rel = i - 61440;
    int e = rel & 7, nn = (rel >> 3) & 15;
    int g = (rel >> 7) % 36, nb = (rel >> 7) / 36;
    int q = g * 8 + e, buf = q / 96, kk = q - buf * 96, n = nb * 16 + nn;
    float f = 0.f;
    if (kk < 75 && n < 150) f = wc1[(buf * 75 + kk) * 150 + n];
    v = (f16)f;
  } else v = pack_one(wc2, i - 107520, 150, 75, 20, 0);
  wp[i] = v;
}

// ---------------- x -> padded f16 ----------------

__global__ __launch_bounds__(256) void convx_kernel(const float* __restrict__ x,
                                                    f16* __restrict__ xp) {
  int i = blockIdx.x * 256 + threadIdx.x;
  if (i >= N2 * 96) return;
  int r = i / 96, c = i - r * 96;
  xp[i] = (f16)((r < NN && c < 75) ? x[r * 75 + c] : 0.f);
}

// ---------------- aggregation: wave per node, 10 lanes x 16B, 6 edges in flight ----------------

__global__ __launch_bounds__(256) void aggz_kernel(const f16* __restrict__ xc,
                                                   const int* __restrict__ rs,
                                                   const int* __restrict__ csr,
                                                   const float* __restrict__ eps,
                                                   f16* __restrict__ zm) {
  int tid = threadIdx.x;
  int l = tid & 63;
  int n = blockIdx.x * 4 + (tid >> 6);
  if (n >= NN) return;
  int s = l / 10, j = l - s * 10;
  int e0 = rs[n], e1 = rs[n + 1];
  float acc[8] = {0, 0, 0, 0, 0, 0, 0, 0};
  if (l < 60) {
#pragma unroll 2
    for (int e = e0 + s; e < e1; e += 6) {
      int sr = csr[e];
      f16x8 v = *(const f16x8*)(xc + sr * 96 + j * 8);
#pragma unroll
      for (int k = 0; k < 8; ++k) acc[k] += (float)v[k];
    }
  }
  int l1 = (l + 30) & 63, l2 = (l + 10) & 63, l3 = (l + 20) & 63;
#pragma unroll
  for (int k = 0; k < 8; ++k) {
    float t = __shfl(acc[k], l1, 64);
    if (l < 30) acc[k] += t;              // s0..2 += s3..5
    t = __shfl(acc[k], l2, 64);
    if (l < 10) acc[k] += t;              // s0 += s1
    t = __shfl(acc[k], l3, 64);
    if (l < 10) acc[k] += t;              // s0 += s2
  }
  if (l < 10) {
    f16x8 self = *(const f16x8*)(xc + n * 96 + j * 8);
    float ep = 1.f + eps[0];
    f16x8 o;
#pragma unroll
    for (int k = 0; k < 8; ++k) o[k] = (f16)(ep * (float)self[k] + acc[k]);
    *(f16x8*)(zm + n * 96 + j * 8) = o;
  }
}

// ---------------- fused GIN-MLP + GRU step (m in LDS, vectorized writeback) ----------------
// All LDS tiles are PER-WAVE (Ls[w]) -> no __syncthreads needed anywhere.

__global__ __launch_bounds__(256) void mlpgru_kernel(const f16* __restrict__ zm,
                                                     const f16* __restrict__ hcur,
                                                     const f16* __restrict__ w1p,
                                                     const f16* __restrict__ w2p,
                                                     const float* __restrict__ b1,
                                                     const float* __restrict__ b2,
                                                     const f16* __restrict__ wihp,
                                                     const f16* __restrict__ whhp,
                                                     const float* __restrict__ bih,
                                                     const float* __restrict__ bhh,
                                                     f16* __restrict__ hb_out,
                                                     float* __restrict__ outx) {
  __shared__ f16 Ls[4][16 * 104];
  int tid = threadIdx.x;
  int w = tid >> 6, l = tid & 63, lm = l & 15, lg = l >> 4;
  int row0 = blockIdx.x * 64 + w * 16;
  // --- MLP layer 1: A from zm (global), acc = z@w1+b1
  const f16* ar = zm + (row0 + lm) * 96;
  f16x8 a0 = *(const f16x8*)(ar + lg * 8);
  f16x8 a1 = *(const f16x8*)(ar + 32 + lg * 8);
  f16x8 a2 = *(const f16x8*)(ar + 64 + lg * 8);
  f32x4 acc[5];
#pragma unroll
  for (int nb = 0; nb < 5; ++nb) {
    int n = nb * 16 + lm;
    float bv = (n < 75) ? b1[n] : 0.f;
    acc[nb] = (f32x4){bv, bv, bv, bv};
    const f16* bp = w1p + ((nb * 12 + lg) * 16 + lm) * 8;
    acc[nb] = MFMA(a0, *(const f16x8*)bp, acc[nb]);
    acc[nb] = MFMA(a1, *(const f16x8*)(bp + 512), acc[nb]);
    acc[nb] = MFMA(a2, *(const f16x8*)(bp + 1024), acc[nb]);
  }
  f16* Ld = Ls[w];
#pragma unroll
  for (int nb = 0; nb < 5; ++nb)
#pragma unroll
    for (int r = 0; r < 4; ++r)
      Ld[(lg * 4 + r) * 104 + nb * 16 + lm] = (f16)fmaxf(acc[nb][r], 0.f);
#pragma unroll
  for (int c = 0; c < 4; ++c) Ld[lm * 104 + 80 + lg * 4 + c] = (f16)0.f;  // zero cols 80..95
  // --- MLP layer 2 (A from LDS, same wave)
  const f16* Lr = Ls[w] + lm * 104;
  f16x8 c0 = *(const f16x8*)(Lr + lg * 8);
  f16x8 c1 = *(const f16x8*)(Lr + 32 + lg * 8);
  f16x8 c2 = *(const f16x8*)(Lr + 64 + lg * 8);
  f32x4 acc2[5];
#pragma unroll
  for (int nb = 0; nb < 5; ++nb) {
    int n = nb * 16 + lm;
    float bv = (n < 75) ? b2[n] : 0.f;
    acc2[nb] = (f32x4){bv, bv, bv, bv};
    const f16* bp = w2p + ((nb * 12 + lg) * 16 + lm) * 8;
    acc2[nb] = MFMA(c0, *(const f16x8*)bp, acc2[nb]);
    acc2[nb] = MFMA(c1, *(const f16x8*)(bp + 512), acc2[nb]);
    acc2[nb] = MFMA(c2, *(const f16x8*)(bp + 1024), acc2[nb]);
  }
  // --- m = relu(...) back to LDS (cols 80..95 still zero)
#pragma unroll
  for (int nb = 0; nb < 5; ++nb)
#pragma unroll
    for (int r = 0; r < 4; ++r)
      Ld[(lg * 4 + r) * 104 + nb * 16 + lm] = (f16)fmaxf(acc2[nb][r], 0.f);
  // --- GRU: m-frags from LDS, h-frags from global
  const f16* mrow = Ls[w] + lm * 104;
  const f16* hr = hcur + (row0 + lm) * 96;
  f16x8 am[3], ah[3];
#pragma unroll
  for (int s = 0; s < 3; ++s) {
    am[s] = *(const f16x8*)(mrow + s * 32 + lg * 8);
    ah[s] = *(const f16x8*)(hr + s * 32 + lg * 8);
  }
  f32x4 rg[5], zg[5], ni[5], nh[5];
#pragma unroll
  for (int nb = 0; nb < 5; ++nb) {
    int n = nb * 16 + lm;
    float br = 0, bz = 0, bi = 0, bh = 0;
    if (n < 75) {
      br = bih[n] + bhh[n];
      bz = bih[75 + n] + bhh[75 + n];
      bi = bih[150 + n];
      bh = bhh[150 + n];
    }
    rg[nb] = (f32x4){br, br, br, br};
    zg[nb] = (f32x4){bz, bz, bz, bz};
    ni[nb] = (f32x4){bi, bi, bi, bi};
    nh[nb] = (f32x4){bh, bh, bh, bh};
#pragma unroll
    for (int s = 0; s < 3; ++s) {
      int fo = ((nb * 12 + s * 4 + lg) * 16 + lm) * 8;
      rg[nb] = MFMA(am[s], *(const f16x8*)(wihp + fo), rg[nb]);
      rg[nb] = MFMA(ah[s], *(const f16x8*)(whhp + fo), rg[nb]);
      zg[nb] = MFMA(am[s], *(const f16x8*)(wihp + 7680 + fo), zg[nb]);
      zg[nb] = MFMA(ah[s], *(const f16x8*)(whhp + 7680 + fo), zg[nb]);
      ni[nb] = MFMA(am[s], *(const f16x8*)(wihp + 15360 + fo), ni[nb]);
      nh[nb] = MFMA(ah[s], *(const f16x8*)(whhp + 15360 + fo), nh[nb]);
    }
  }
  // --- gates -> h' into LDS (cols 0..79; 80..95 remain zero)
#pragma unroll
  for (int nb = 0; nb < 5; ++nb)
#pragma unroll
    for (int r = 0; r < 4; ++r) {
      int n = nb * 16 + lm;
      int grow = row0 + lg * 4 + r;
      float hval = (float)hcur[grow * 96 + n];
      float rv = 1.f / (1.f + __expf(-rg[nb][r]));
      float zv = 1.f / (1.f + __expf(-zg[nb][r]));
      float nv = tanhf(ni[nb][r] + rv * nh[nb][r]);
      float hp = (1.f - zv) * nv + zv * hval;
      Ld[(lg * 4 + r) * 104 + n] = (f16)hp;
    }
  // --- vectorized coalesced writeback: 16 rows x 96 f16 = 192 f16x8
#pragma unroll
  for (int k = 0; k < 3; ++k) {
    int p = l + 64 * k;
    int r = p / 12, sl = p - r * 12;
    f16x8 v = *(const f16x8*)(Ld + r * 104 + sl * 8);
    *(f16x8*)(hb_out + (row0 + r) * 96 + sl * 8) = v;
  }
  if (outx) {
    // fp32 final-h: 16 rows x 75 floats contiguous
    for (int k = 0; k < 19; ++k) {
      int p = l + 64 * k;
      int gi = row0 * 75 + p;
      if (p < 1200 && gi < NN * 75) {
        int r = p / 75, c = p - r * 75;
        outx[gi] = (float)Ld[r * 104 + c];
      }
    }
  }
}

// ---------------- fused readout from hb0/hb1/hb2 (r1 in LDS, per-wave) ----------------

__global__ __launch_bounds__(256) void readout_kernel(const f16* __restrict__ hb0,
                                                      const f16* __restrict__ hb1,
                                                      const f16* __restrict__ hb2,
                                                      const f16* __restrict__ wc1p,
                                                      const float* __restrict__ bc1,
                                                      const f16* __restrict__ wc2p,
                                                      const float* __restrict__ bc2,
                                                      float* __restrict__ out) {
  __shared__ f16 Ls[4][16 * 168];
  int tid = threadIdx.x;
  int w = tid >> 6, l = tid & 63, lm = l & 15, lg = l >> 4;
  int row0 = blockIdx.x * 64 + w * 16;
  int row = row0 + lm;
  f16x8 a[9];
#pragma unroll
  for (int s = 0; s < 9; ++s) {
    const f16* hb = (s < 3) ? hb0 : (s < 6) ? hb1 : hb2;
    a[s] = *(const f16x8*)(hb + row * 96 + (4 * (s - (s / 3) * 3) + lg) * 8);
  }
  f32x4 acc[10];
#pragma unroll
  for (int nb = 0; nb < 10; ++nb) {
    int n = nb * 16 + lm;
    float bv = (n < 150) ? bc1[n] : 0.f;
    acc[nb] = (f32x4){bv, bv, bv, bv};
#pragma unroll
    for (int s = 0; s < 9; ++s)
      acc[nb] = MFMA(a[s], *(const f16x8*)(wc1p + ((nb * 36 + 4 * s + lg) * 16 + lm) * 8),
                     acc[nb]);
  }
  f16* Ld = Ls[w];
#pragma unroll
  for (int nb = 0; nb < 10; ++nb)
#pragma unroll
    for (int r = 0; r < 4; ++r)
      Ld[(lg * 4 + r) * 168 + nb * 16 + lm] = (f16)fmaxf(acc[nb][r], 0.f);
  const f16* Lr = Ls[w] + lm * 168;
  f16x8 a2[5];
#pragma unroll
  for (int s = 0; s < 5; ++s) a2[s] = *(const f16x8*)(Lr + s * 32 + lg * 8);
  f32x4 acc2[5];
#pragma unroll
  for (int nb = 0; nb < 5; ++nb) {
    int n = nb * 16 + lm;
    float bv = (n < 75) ? bc2[n] : 0.f;
    acc2[nb] = (f32x4){bv, bv, bv, bv};
#pragma unroll
    for (int s = 0; s < 5; ++s)
      acc2[nb] = MFMA(a2[s], *(const f16x8*)(wc2p + ((nb * 20 + s * 4 + lg) * 16 + lm) * 8),
                     acc2[nb]);
  }
  // fp32 restage (per-wave) -> contiguous stores
  float* Lf = (float*)Ls[w];
#pragma unroll
  for (int nb = 0; nb < 5; ++nb)
#pragma unroll
    for (int r = 0; r < 4; ++r) {
      int n = nb * 16 + lm;
      if (n < 75) Lf[(lg * 4 + r) * 76 + n] = acc2[nb][r];
    }
  for (int k = 0; k < 19; ++k) {
    int p = l + 64 * k;
    int gi = row0 * 75 + p;
    if (p < 1200 && gi < NN * 75) {
      int r = p / 75, c = p - r * 75;
      out[gi] = Lf[r * 76 + c];
    }
  }
}

// ---------------- launch ----------------

extern "C" void kernel_launch(void* const* d_in, const int* in_sizes, int n_in,
                              void* d_out, int out_size, void* d_ws, size_t ws_size,
                              hipStream_t stream) {
  const float* x    = (const float*)d_in[0];
  const int*   ei   = (const int*)d_in[1];
  const float* eps  = (const float*)d_in[2];
  const float* w1   = (const float*)d_in[3];
  const float* b1   = (const float*)d_in[4];
  const float* w2   = (const float*)d_in[5];
  const float* b2   = (const float*)d_in[6];
  const float* w_ih = (const float*)d_in[7];
  const float* w_hh = (const float*)d_in[8];
  const float* b_ih = (const float*)d_in[9];
  const float* b_hh = (const float*)d_in[10];
  const float* wc1  = (const float*)d_in[11];
  const float* bc1  = (const float*)d_in[12];
  const float* wc2  = (const float*)d_in[13];
  const float* bc2  = (const float*)d_in[14];

  const int* srcv = ei;
  const int* dstv = ei + EE;

  float* out_x = (float*)d_out;              // N*75 final node states (fp32)
  float* out_r = out_x + NN * 75;            // N*75 readout (fp32)

  f16* zm   = (f16*)d_ws;                    // N2*96
  f16* x0   = zm + (size_t)N2 * 96;          // N2*96 (initial x, f16-padded)
  f16* hb0  = x0 + (size_t)N2 * 96;          // N2*96
  f16* hb1  = hb0 + (size_t)N2 * 96;         // N2*96
  f16* hb2  = hb1 + (size_t)N2 * 96;         // N2*96
  f16* wp   = hb2 + (size_t)N2 * 96;         // packed weights, 120320 f16
  f16* w1p  = wp;
  f16* w2p  = wp + 7680;
  f16* wihp = wp + 15360;                    // 3 gates x 7680
  f16* whhp = wp + 38400;
  f16* wc1p = wp + 61440;                    // 46080 (KG=36, NB=10)
  f16* wc2p = wp + 107520;                   // 12800
  u32* ebuf = (u32*)(wp + 120320);           // EE
  int* csr  = (int*)(ebuf + EE);             // EE
  int* rsv  = csr + EE;                      // NN+1
  int* bbase = rsv + NN + 1;                 // NBUCK+1
  int* bcur  = bbase + NBUCK + 1;            // NBUCK*CPAD
  int* bcnt  = bcur + NBUCK * CPAD;          // NBUCK*CPAD

  hipMemsetAsync(bcnt, 0, NBUCK * CPAD * sizeof(int), stream);
  bhist_kernel<<<512, 256, 0, stream>>>((const int4*)dstv, bcnt);
  bscan_kernel<<<1, 1024, 0, stream>>>(bcnt, bbase, bcur, rsv);
  binB_kernel<<<(EE + CHUNK - 1) / CHUNK, 256, 0, stream>>>(srcv, dstv, bcur, ebuf);
  binC_kernel<<<NBUCK, 256, 0, stream>>>(ebuf, bbase, rsv, csr);
  convx_kernel<<<(N2 * 96 + 255) / 256, 256, 0, stream>>>(x, x0);
  packall_kernel<<<470, 256, 0, stream>>>(w1, w2, w_ih, w_hh, wc1, wc2, wp);

  int gb = N2 / 64;  // 1563
  f16* hbs[3] = {hb0, hb1, hb2};
  for (int it = 0; it < 3; ++it) {
    const f16* h = (it == 0) ? x0 : hbs[it - 1];
    aggz_kernel<<<25000, 256, 0, stream>>>(h, rsv, csr, eps, zm);
    mlpgru_kernel<<<gb, 256, 0, stream>>>(zm, h, w1p, w2p, b1, b2, wihp, whhp, b_ih, b_hh,
                                          hbs[it], (it == 2) ? out_x : nullptr);
  }
  readout_kernel<<<gb, 256, 0, stream>>>(hb0, hb1, hb2, wc1p, bc1, wc2p, bc2, out_r);
}

// Round 8
// 667.257 us; speedup vs baseline: 2.1285x; 1.0568x over previous
//
#include <hip/hip_runtime.h>

#define NN 100000
#define EE 3200000
#define N2 100032   // NN rounded up to 64
#define NBUCK 782   // ceil(NN/128)
#define CPAD 16     // counter padding (one per 64B line)
#define CHUNK 12288 // edges per binB block

typedef _Float16 f16;
typedef _Float16 f16x8 __attribute__((ext_vector_type(8)));
typedef float f32x4 __attribute__((ext_vector_type(4)));
typedef unsigned int u32;

#define MFMA(a, b, c) __builtin_amdgcn_mfma_f32_16x16x32_f16((a), (b), (c), 0, 0, 0)

// ---------------- CSR build (binned two-phase, contention-free) ----------------

__global__ __launch_bounds__(256) void bhist_kernel(const int4* __restrict__ dst4,
                                                    int* __restrict__ bcnt) {
  __shared__ int h[2][NBUCK];
  int tid = threadIdx.x;
  for (int i = tid; i < 2 * NBUCK; i += 256) ((int*)h)[i] = 0;
  __syncthreads();
  int r = (tid >> 7) & 1;
  for (int i = blockIdx.x * 256 + tid; i < EE / 4; i += gridDim.x * 256) {
    int4 d = dst4[i];
    atomicAdd(&h[r][d.x >> 7], 1);
    atomicAdd(&h[r][d.y >> 7], 1);
    atomicAdd(&h[r][d.z >> 7], 1);
    atomicAdd(&h[r][d.w >> 7], 1);
  }
  __syncthreads();
  for (int i = tid; i < NBUCK; i += 256) {
    int v = h[0][i] + h[1][i];
    if (v) atomicAdd(&bcnt[i * CPAD], v);
  }
}

__global__ __launch_bounds__(1024) void bscan_kernel(const int* __restrict__ bcnt,
                                                     int* __restrict__ bbase,
                                                     int* __restrict__ bcur,
                                                     int* __restrict__ rs) {
  __shared__ int sb[1024];
  int tid = threadIdx.x;
  int c = (tid < NBUCK) ? bcnt[tid * CPAD] : 0;
  int v = c;
  sb[tid] = v;
  __syncthreads();
  for (int off = 1; off < 1024; off <<= 1) {
    int t = (tid >= off) ? sb[tid - off] : 0;
    __syncthreads();
    v += t;
    sb[tid] = v;
    __syncthreads();
  }
  if (tid < NBUCK) {
    bbase[tid] = v - c;
    bcur[tid * CPAD] = v - c;
  }
  if (tid == 0) {
    bbase[NBUCK] = EE;
    rs[NN] = EE;
  }
}

__global__ __launch_bounds__(256) void binB_kernel(const int* __restrict__ src,
                                                   const int* __restrict__ dst,
                                                   int* __restrict__ bcur,
                                                   u32* __restrict__ ebuf) {
  __shared__ int hist[NBUCK];
  __shared__ int base[NBUCK];
  int tid = threadIdx.x;
  int e0 = blockIdx.x * CHUNK;
  int e1 = e0 + CHUNK;
  if (e1 > EE) e1 = EE;
  for (int i = tid; i < NBUCK; i += 256) hist[i] = 0;
  __syncthreads();
  for (int e = e0 + tid * 4; e < e1; e += 1024) {
    int4 d = *(const int4*)(dst + e);
    atomicAdd(&hist[d.x >> 7], 1);
    atomicAdd(&hist[d.y >> 7], 1);
    atomicAdd(&hist[d.z >> 7], 1);
    atomicAdd(&hist[d.w >> 7], 1);
  }
  __syncthreads();
  for (int i = tid; i < NBUCK; i += 256) {
    int c = hist[i];
    if (c) base[i] = atomicAdd(&bcur[i * CPAD], c);
  }
  __syncthreads();
  for (int i = tid; i < NBUCK; i += 256) hist[i] = 0;
  __syncthreads();
  for (int e = e0 + tid * 4; e < e1; e += 1024) {
    int4 d = *(const int4*)(dst + e);
    int4 s = *(const int4*)(src + e);
    int b, loc;
    b = d.x >> 7; loc = atomicAdd(&hist[b], 1);
    ebuf[base[b] + loc] = (u32)s.x | ((u32)(d.x & 127) << 17);
    b = d.y >> 7; loc = atomicAdd(&hist[b], 1);
    ebuf[base[b] + loc] = (u32)s.y | ((u32)(d.y & 127) << 17);
    b = d.z >> 7; loc = atomicAdd(&hist[b], 1);
    ebuf[base[b] + loc] = (u32)s.z | ((u32)(d.z & 127) << 17);
    b = d.w >> 7; loc = atomicAdd(&hist[b], 1);
    ebuf[base[b] + loc] = (u32)s.w | ((u32)(d.w & 127) << 17);
  }
}

__global__ __launch_bounds__(256) void binC_kernel(const u32* __restrict__ ebuf,
                                                   const int* __restrict__ bbase,
                                                   int* __restrict__ rs,
                                                   int* __restrict__ csr) {
  __shared__ int cnt[128], sc[128], cur[128];
  int b = blockIdx.x, tid = threadIdx.x;
  int e0 = bbase[b], e1 = bbase[b + 1];
  if (tid < 128) cnt[tid] = 0;
  __syncthreads();
  for (int e = e0 + tid; e < e1; e += 256) atomicAdd(&cnt[ebuf[e] >> 17], 1);
  __syncthreads();
  if (tid < 128) sc[tid] = cnt[tid];
  __syncthreads();
  for (int off = 1; off < 128; off <<= 1) {
    int t = 0;
    if (tid < 128 && tid >= off) t = sc[tid - off];
    __syncthreads();
    if (tid < 128) sc[tid] += t;
    __syncthreads();
  }
  if (tid < 128) {
    int gpos = e0 + sc[tid] - cnt[tid];
    int node = b * 128 + tid;
    if (node < NN) rs[node] = gpos;
    cur[tid] = gpos;
  }
  __syncthreads();
  for (int e = e0 + tid; e < e1; e += 256) {
    u32 p = ebuf[e];
    int pos = atomicAdd(&cur[p >> 17], 1);
    csr[pos] = (int)(p & 0x1FFFFu);
  }
}

// ---------------- all weight packs in one kernel (B-fragment order, bias folded at k=95/159) ----

__device__ __forceinline__ f16 pack_one(const float* __restrict__ W,
                                        const float* __restrict__ bias, int rel, int K, int Nc,
                                        int KG, int trans, int bslot) {
  int e = rel & 7, nn = (rel >> 3) & 15;
  int g = (rel >> 7) % KG, nb = (rel >> 7) / KG;
  int k = g * 8 + e, n = nb * 16 + nn;
  float v = 0.f;
  if (n < Nc) {
    if (k < K) v = trans ? W[n * K + k] : W[k * Nc + n];
    else if (k == bslot) v = bias[n];
  }
  return (f16)v;
}

__global__ __launch_bounds__(256) void packall_kernel(const float* __restrict__ w1,
                                                      const float* __restrict__ b1,
                                                      const float* __restrict__ w2,
                                                      const float* __restrict__ b2,
                                                      const float* __restrict__ wih,
                                                      const float* __restrict__ bih,
                                                      const float* __restrict__ whh,
                                                      const float* __restrict__ bhh,
                                                      const float* __restrict__ wc1,
                                                      const float* __restrict__ bc1,
                                                      const float* __restrict__ wc2,
                                                      const float* __restrict__ bc2,
                                                      f16* __restrict__ wp) {
  int i = blockIdx.x * 256 + threadIdx.x;
  if (i >= 120320) return;
  f16 v;
  if (i < 7680) v = pack_one(w1, b1, i, 75, 75, 12, 0, 95);
  else if (i < 15360) v = pack_one(w2, b2, i - 7680, 75, 75, 12, 0, 95);
  else if (i < 38400) {
    int r = i - 15360, g = r / 7680;
    v = pack_one(wih + g * 5625, bih + g * 75, r - g * 7680, 75, 75, 12, 1, 95);
  } else if (i < 61440) {
    int r = i - 38400, g = r / 7680;
    v = pack_one(whh + g * 5625, bhh + g * 75, r - g * 7680, 75, 75, 12, 1, 95);
  } else if (i < 107520) {
    // wc1 remap: 288 k-slots = 3 x (75 valid + pad); buf0 slot95 carries bc1
    int rel = i - 61440;
    int e = rel & 7, nn = (rel >> 3) & 15;
    int g = (rel >> 7) % 36, nb = (rel >> 7) / 36;
    int q = g * 8 + e, buf = q / 96, kk = q - buf * 96, n = nb * 16 + nn;
    float f = 0.f;
    if (n < 150) {
      if (kk < 75) f = wc1[(buf * 75 + kk) * 150 + n];
      else if (kk == 95 && buf == 0) f = bc1[n];
    }
    v = (f16)f;
  } else v = pack_one(wc2, bc2, i - 107520, 150, 75, 20, 0, 159);
  wp[i] = v;
}

// ---------------- x -> padded f16 (col 95 = 1 for bias slot) ----------------

__global__ __launch_bounds__(256) void convx_kernel(const float* __restrict__ x,
                                                    f16* __restrict__ xp) {
  int i = blockIdx.x * 256 + threadIdx.x;
  if (i >= N2 * 96) return;
  int r = i / 96, c = i - r * 96;
  float v = (r < NN && c < 75) ? x[r * 75 + c] : (c == 95 ? 1.f : 0.f);
  xp[i] = (f16)v;
}

// zm pad cols 80..94 = 0, col 95 = 1 (aggz only writes cols 0..79)
__global__ __launch_bounds__(256) void zminit_kernel(f16* __restrict__ zm) {
  int i = blockIdx.x * 256 + threadIdx.x;
  if (i >= N2 * 16) return;
  int r = i >> 4, c = i & 15;
  zm[r * 96 + 80 + c] = (f16)(c == 15 ? 1.f : 0.f);
}

// ---------------- aggregation: wave per node, 10 lanes x 16B, 6 edges in flight ----------------

__global__ __launch_bounds__(256) void aggz_kernel(const f16* __restrict__ xc,
                                                   const int* __restrict__ rs,
                                                   const int* __restrict__ csr,
                                                   const float* __restrict__ eps,
                                                   f16* __restrict__ zm) {
  int tid = threadIdx.x;
  int l = tid & 63;
  int n = blockIdx.x * 4 + (tid >> 6);
  if (n >= NN) return;
  int s = l / 10, j = l - s * 10;
  int e0 = rs[n], e1 = rs[n + 1];
  float acc[8] = {0, 0, 0, 0, 0, 0, 0, 0};
  if (l < 60) {
#pragma unroll 2
    for (int e = e0 + s; e < e1; e += 6) {
      int sr = csr[e];
      f16x8 v = *(const f16x8*)(xc + sr * 96 + j * 8);
#pragma unroll
      for (int k = 0; k < 8; ++k) acc[k] += (float)v[k];
    }
  }
  int l1 = (l + 30) & 63, l2 = (l + 10) & 63, l3 = (l + 20) & 63;
#pragma unroll
  for (int k = 0; k < 8; ++k) {
    float t = __shfl(acc[k], l1, 64);
    if (l < 30) acc[k] += t;
    t = __shfl(acc[k], l2, 64);
    if (l < 10) acc[k] += t;
    t = __shfl(acc[k], l3, 64);
    if (l < 10) acc[k] += t;
  }
  if (l < 10) {
    f16x8 self = *(const f16x8*)(xc + n * 96 + j * 8);
    float ep = 1.f + eps[0];
    f16x8 o;
#pragma unroll
    for (int k = 0; k < 8; ++k) o[k] = (f16)(ep * (float)self[k] + acc[k]);
    *(f16x8*)(zm + n * 96 + j * 8) = o;
  }
}

// ---------------- fused GIN-MLP + GRU (all loads hoisted, h staged in LDS, biases in weights) ---

__global__ __launch_bounds__(256) void mlpgru_kernel(const f16* __restrict__ zm,
                                                     const f16* __restrict__ hcur,
                                                     const f16* __restrict__ w1p,
                                                     const f16* __restrict__ w2p,
                                                     const f16* __restrict__ wihp,
                                                     const f16* __restrict__ whhp,
                                                     f16* __restrict__ hb_out,
                                                     float* __restrict__ outx) {
  __shared__ f16 Ls[4][16 * 104];
  __shared__ f16 Hs[4][16 * 104];
  int tid = threadIdx.x;
  int w = tid >> 6, l = tid & 63, lm = l & 15, lg = l >> 4;
  int row0 = blockIdx.x * 64 + w * 16;
  // hoist ALL global loads (6 x 16B per lane in flight)
  const f16* ar = zm + (row0 + lm) * 96;
  const f16* hr = hcur + (row0 + lm) * 96;
  f16x8 a0 = *(const f16x8*)(ar + lg * 8);
  f16x8 a1 = *(const f16x8*)(ar + 32 + lg * 8);
  f16x8 a2 = *(const f16x8*)(ar + 64 + lg * 8);
  f16x8 h0 = *(const f16x8*)(hr + lg * 8);
  f16x8 h1 = *(const f16x8*)(hr + 32 + lg * 8);
  f16x8 h2 = *(const f16x8*)(hr + 64 + lg * 8);
  // stage h for transposed epilogue access
  f16* Hd = Hs[w];
  *(f16x8*)(Hd + lm * 104 + lg * 8) = h0;
  *(f16x8*)(Hd + lm * 104 + 32 + lg * 8) = h1;
  *(f16x8*)(Hd + lm * 104 + 64 + lg * 8) = h2;
  // --- MLP layer 1 (bias folded: zm col95=1, w1p k95=b1)
  f32x4 acc[5];
#pragma unroll
  for (int nb = 0; nb < 5; ++nb) {
    acc[nb] = (f32x4){0.f, 0.f, 0.f, 0.f};
    const f16* bp = w1p + ((nb * 12 + lg) * 16 + lm) * 8;
    acc[nb] = MFMA(a0, *(const f16x8*)bp, acc[nb]);
    acc[nb] = MFMA(a1, *(const f16x8*)(bp + 512), acc[nb]);
    acc[nb] = MFMA(a2, *(const f16x8*)(bp + 1024), acc[nb]);
  }
  f16* Ld = Ls[w];
#pragma unroll
  for (int nb = 0; nb < 5; ++nb)
#pragma unroll
    for (int r = 0; r < 4; ++r)
      Ld[(lg * 4 + r) * 104 + nb * 16 + lm] = (f16)fmaxf(acc[nb][r], 0.f);
#pragma unroll
  for (int c = 0; c < 4; ++c) {
    int col = 80 + lg * 4 + c;
    Ld[lm * 104 + col] = (f16)(col == 95 ? 1.f : 0.f);  // pad + bias-slot 1
  }
  // --- MLP layer 2 (m col95=1, w2p k95=b2)
  const f16* Lr = Ls[w] + lm * 104;
  f16x8 c0 = *(const f16x8*)(Lr + lg * 8);
  f16x8 c1 = *(const f16x8*)(Lr + 32 + lg * 8);
  f16x8 c2 = *(const f16x8*)(Lr + 64 + lg * 8);
  f32x4 acc2[5];
#pragma unroll
  for (int nb = 0; nb < 5; ++nb) {
    acc2[nb] = (f32x4){0.f, 0.f, 0.f, 0.f};
    const f16* bp = w2p + ((nb * 12 + lg) * 16 + lm) * 8;
    acc2[nb] = MFMA(c0, *(const f16x8*)bp, acc2[nb]);
    acc2[nb] = MFMA(c1, *(const f16x8*)(bp + 512), acc2[nb]);
    acc2[nb] = MFMA(c2, *(const f16x8*)(bp + 1024), acc2[nb]);
  }
#pragma unroll
  for (int nb = 0; nb < 5; ++nb)
#pragma unroll
    for (int r = 0; r < 4; ++r)
      Ld[(lg * 4 + r) * 104 + nb * 16 + lm] = (f16)fmaxf(acc2[nb][r], 0.f);
  // --- GRU: m from LDS (col95=1 -> bih), h frags in regs (col95=1 -> bhh)
  const f16* mrow = Ls[w] + lm * 104;
  f16x8 am[3];
#pragma unroll
  for (int s = 0; s < 3; ++s) am[s] = *(const f16x8*)(mrow + s * 32 + lg * 8);
  f16x8 ah[3] = {h0, h1, h2};
  f32x4 rg[5], zg[5], ni[5], nh[5];
#pragma unroll
  for (int nb = 0; nb < 5; ++nb) {
    rg[nb] = (f32x4){0.f, 0.f, 0.f, 0.f};
    zg[nb] = rg[nb]; ni[nb] = rg[nb]; nh[nb] = rg[nb];
#pragma unroll
    for (int s = 0; s < 3; ++s) {
      int fo = ((nb * 12 + s * 4 + lg) * 16 + lm) * 8;
      rg[nb] = MFMA(am[s], *(const f16x8*)(wihp + fo), rg[nb]);
      rg[nb] = MFMA(ah[s], *(const f16x8*)(whhp + fo), rg[nb]);
      zg[nb] = MFMA(am[s], *(const f16x8*)(wihp + 7680 + fo), zg[nb]);
      zg[nb] = MFMA(ah[s], *(const f16x8*)(whhp + 7680 + fo), zg[nb]);
      ni[nb] = MFMA(am[s], *(const f16x8*)(wihp + 15360 + fo), ni[nb]);
      nh[nb] = MFMA(ah[s], *(const f16x8*)(whhp + 15360 + fo), nh[nb]);
    }
  }
  // --- gates -> h' into LDS (cols 0..79; pads stay 0 / col95=1)
#pragma unroll
  for (int nb = 0; nb < 5; ++nb)
#pragma unroll
    for (int r = 0; r < 4; ++r) {
      int n = nb * 16 + lm;
      float hval = (float)Hd[(lg * 4 + r) * 104 + n];
      float rv = 1.f / (1.f + __expf(-rg[nb][r]));
      float zv = 1.f / (1.f + __expf(-zg[nb][r]));
      float u = ni[nb][r] + rv * nh[nb][r];
      float t = __expf(-2.f * fabsf(u));
      float nv = copysignf((1.f - t) / (1.f + t), u);
      float hp = zv * (hval - nv) + nv;
      Ld[(lg * 4 + r) * 104 + n] = (f16)hp;
    }
  // --- vectorized coalesced writeback: 16 rows x 96 f16
#pragma unroll
  for (int k = 0; k < 3; ++k) {
    int p = l + 64 * k;
    int r = p / 12, sl = p - r * 12;
    f16x8 v = *(const f16x8*)(Ld + r * 104 + sl * 8);
    *(f16x8*)(hb_out + (row0 + r) * 96 + sl * 8) = v;
  }
  if (outx) {
    for (int k = 0; k < 19; ++k) {
      int p = l + 64 * k;
      int gi = row0 * 75 + p;
      if (p < 1200 && gi < NN * 75) {
        int r = p / 75, c = p - r * 75;
        outx[gi] = (float)Ld[r * 104 + c];
      }
    }
  }
}

// ---------------- fused readout (biases folded; r1 col159=1 -> bc2) ----------------

__global__ __launch_bounds__(256) void readout_kernel(const f16* __restrict__ hb0,
                                                      const f16* __restrict__ hb1,
                                                      const f16* __restrict__ hb2,
                                                      const f16* __restrict__ wc1p,
                                                      const f16* __restrict__ wc2p,
                                                      float* __restrict__ out) {
  __shared__ f16 Ls[4][16 * 168];
  int tid = threadIdx.x;
  int w = tid >> 6, l = tid & 63, lm = l & 15, lg = l >> 4;
  int row0 = blockIdx.x * 64 + w * 16;
  int row = row0 + lm;
  f16x8 a[9];
#pragma unroll
  for (int s = 0; s < 9; ++s) {
    const f16* hb = (s < 3) ? hb0 : (s < 6) ? hb1 : hb2;
    a[s] = *(const f16x8*)(hb + row * 96 + (4 * (s - (s / 3) * 3) + lg) * 8);
  }
  f32x4 acc[10];
#pragma unroll
  for (int nb = 0; nb < 10; ++nb) {
    acc[nb] = (f32x4){0.f, 0.f, 0.f, 0.f};
#pragma unroll
    for (int s = 0; s < 9; ++s)
      acc[nb] = MFMA(a[s], *(const f16x8*)(wc1p + ((nb * 36 + 4 * s + lg) * 16 + lm) * 8),
                     acc[nb]);
  }
  f16* Ld = Ls[w];
#pragma unroll
  for (int nb = 0; nb < 10; ++nb)
#pragma unroll
    for (int r = 0; r < 4; ++r) {
      int n = nb * 16 + lm;
      float v = fmaxf(acc[nb][r], 0.f);
      if (n >= 150) v = (n == 159) ? 1.f : 0.f;   // pad + bias slot
      Ld[(lg * 4 + r) * 168 + n] = (f16)v;
    }
  const f16* Lr = Ls[w] + lm * 168;
  f16x8 a2[5];
#pragma unroll
  for (int s = 0; s < 5; ++s) a2[s] = *(const f16x8*)(Lr + s * 32 + lg * 8);
  f32x4 acc2[5];
#pragma unroll
  for (int nb = 0; nb < 5; ++nb) {
    acc2[nb] = (f32x4){0.f, 0.f, 0.f, 0.f};
#pragma unroll
    for (int s = 0; s < 5; ++s)
      acc2[nb] = MFMA(a2[s], *(const f16x8*)(wc2p + ((nb * 20 + s * 4 + lg) * 16 + lm) * 8),
                     acc2[nb]);
  }
  float* Lf = (float*)Ls[w];
#pragma unroll
  for (int nb = 0; nb < 5; ++nb)
#pragma unroll
    for (int r = 0; r < 4; ++r) {
      int n = nb * 16 + lm;
      if (n < 75) Lf[(lg * 4 + r) * 76 + n] = acc2[nb][r];
    }
  for (int k = 0; k < 19; ++k) {
    int p = l + 64 * k;
    int gi = row0 * 75 + p;
    if (p < 1200 && gi < NN * 75) {
      int r = p / 75, c = p - r * 75;
      out[gi] = Lf[r * 76 + c];
    }
  }
}

// ---------------- launch ----------------

extern "C" void kernel_launch(void* const* d_in, const int* in_sizes, int n_in,
                              void* d_out, int out_size, void* d_ws, size_t ws_size,
                              hipStream_t stream) {
  const float* x    = (const float*)d_in[0];
  const int*   ei   = (const int*)d_in[1];
  const float* eps  = (const float*)d_in[2];
  const float* w1   = (const float*)d_in[3];
  const float* b1   = (const float*)d_in[4];
  const float* w2   = (const float*)d_in[5];
  const float* b2   = (const float*)d_in[6];
  const float* w_ih = (const float*)d_in[7];
  const float* w_hh = (const float*)d_in[8];
  const float* b_ih = (const float*)d_in[9];
  const float* b_hh = (const float*)d_in[10];
  const float* wc1  = (const float*)d_in[11];
  const float* bc1  = (const float*)d_in[12];
  const float* wc2  = (const float*)d_in[13];
  const float* bc2  = (const float*)d_in[14];

  const int* srcv = ei;
  const int* dstv = ei + EE;

  float* out_x = (float*)d_out;              // N*75 final node states (fp32)
  float* out_r = out_x + NN * 75;            // N*75 readout (fp32)

  f16* zm   = (f16*)d_ws;                    // N2*96
  f16* x0   = zm + (size_t)N2 * 96;          // N2*96
  f16* hb0  = x0 + (size_t)N2 * 96;          // N2*96
  f16* hb1  = hb0 + (size_t)N2 * 96;         // N2*96
  f16* hb2  = hb1 + (size_t)N2 * 96;         // N2*96
  f16* wp   = hb2 + (size_t)N2 * 96;         // packed weights, 120320 f16
  f16* w1p  = wp;
  f16* w2p  = wp + 7680;
  f16* wihp = wp + 15360;                    // 3 gates x 7680
  f16* whhp = wp + 38400;
  f16* wc1p = wp + 61440;                    // 46080 (KG=36, NB=10)
  f16* wc2p = wp + 107520;                   // 12800
  u32* ebuf = (u32*)(wp + 120320);           // EE
  int* csr  = (int*)(ebuf + EE);             // EE
  int* rsv  = csr + EE;                      // NN+1
  int* bbase = rsv + NN + 1;                 // NBUCK+1
  int* bcur  = bbase + NBUCK + 1;            // NBUCK*CPAD
  int* bcnt  = bcur + NBUCK * CPAD;          // NBUCK*CPAD

  hipMemsetAsync(bcnt, 0, NBUCK * CPAD * sizeof(int), stream);
  bhist_kernel<<<512, 256, 0, stream>>>((const int4*)dstv, bcnt);
  bscan_kernel<<<1, 1024, 0, stream>>>(bcnt, bbase, bcur, rsv);
  binB_kernel<<<(EE + CHUNK - 1) / CHUNK, 256, 0, stream>>>(srcv, dstv, bcur, ebuf);
  binC_kernel<<<NBUCK, 256, 0, stream>>>(ebuf, bbase, rsv, csr);
  convx_kernel<<<(N2 * 96 + 255) / 256, 256, 0, stream>>>(x, x0);
  zminit_kernel<<<(N2 * 16 + 255) / 256, 256, 0, stream>>>(zm);
  packall_kernel<<<470, 256, 0, stream>>>(w1, b1, w2, b2, w_ih, b_ih, w_hh, b_hh,
                                          wc1, bc1, wc2, bc2, wp);

  int gb = N2 / 64;  // 1563
  f16* hbs[3] = {hb0, hb1, hb2};
  for (int it = 0; it < 3; ++it) {
    const f16* h = (it == 0) ? x0 : hbs[it - 1];
    aggz_kernel<<<25000, 256, 0, stream>>>(h, rsv, csr, eps, zm);
    mlpgru_kernel<<<gb, 256, 0, stream>>>(zm, h, w1p, w2p, wihp, whhp,
                                          hbs[it], (it == 2) ? out_x : nullptr);
  }
  readout_kernel<<<gb, 256, 0, stream>>>(hb0, hb1, hb2, wc1p, wc2p, out_r);
}

// Round 9
// 582.975 us; speedup vs baseline: 2.4362x; 1.1446x over previous
//
#include <hip/hip_runtime.h>

#define NN 100000
#define EE 3200000
#define N2 100032   // NN rounded up to 64
#define NBUCK 782   // ceil(NN/128)
#define CPAD 16     // counter padding (one per 64B line)
#define CHUNK 12288 // edges per binB block

typedef _Float16 f16;
typedef _Float16 f16x8 __attribute__((ext_vector_type(8)));
typedef float f32x4 __attribute__((ext_vector_type(4)));
typedef unsigned int u32;

#define MFMA(a, b, c) __builtin_amdgcn_mfma_f32_16x16x32_f16((a), (b), (c), 0, 0, 0)

// ---------------- CSR build (binned two-phase, contention-free) ----------------

__global__ __launch_bounds__(256) void bhist_kernel(const int4* __restrict__ dst4,
                                                    int* __restrict__ bcnt) {
  __shared__ int h[2][NBUCK];
  int tid = threadIdx.x;
  for (int i = tid; i < 2 * NBUCK; i += 256) ((int*)h)[i] = 0;
  __syncthreads();
  int r = (tid >> 7) & 1;
  for (int i = blockIdx.x * 256 + tid; i < EE / 4; i += gridDim.x * 256) {
    int4 d = dst4[i];
    atomicAdd(&h[r][d.x >> 7], 1);
    atomicAdd(&h[r][d.y >> 7], 1);
    atomicAdd(&h[r][d.z >> 7], 1);
    atomicAdd(&h[r][d.w >> 7], 1);
  }
  __syncthreads();
  for (int i = tid; i < NBUCK; i += 256) {
    int v = h[0][i] + h[1][i];
    if (v) atomicAdd(&bcnt[i * CPAD], v);
  }
}

__global__ __launch_bounds__(1024) void bscan_kernel(const int* __restrict__ bcnt,
                                                     int* __restrict__ bbase,
                                                     int* __restrict__ bcur,
                                                     int* __restrict__ rs) {
  __shared__ int sb[1024];
  int tid = threadIdx.x;
  int c = (tid < NBUCK) ? bcnt[tid * CPAD] : 0;
  int v = c;
  sb[tid] = v;
  __syncthreads();
  for (int off = 1; off < 1024; off <<= 1) {
    int t = (tid >= off) ? sb[tid - off] : 0;
    __syncthreads();
    v += t;
    sb[tid] = v;
    __syncthreads();
  }
  if (tid < NBUCK) {
    bbase[tid] = v - c;
    bcur[tid * CPAD] = v - c;
  }
  if (tid == 0) {
    bbase[NBUCK] = EE;
    rs[NN] = EE;
  }
}

__global__ __launch_bounds__(256) void binB_kernel(const int* __restrict__ src,
                                                   const int* __restrict__ dst,
                                                   int* __restrict__ bcur,
                                                   u32* __restrict__ ebuf) {
  __shared__ int hist[NBUCK];
  __shared__ int base[NBUCK];
  int tid = threadIdx.x;
  int e0 = blockIdx.x * CHUNK;
  int e1 = e0 + CHUNK;
  if (e1 > EE) e1 = EE;
  for (int i = tid; i < NBUCK; i += 256) hist[i] = 0;
  __syncthreads();
  for (int e = e0 + tid * 4; e < e1; e += 1024) {
    int4 d = *(const int4*)(dst + e);
    atomicAdd(&hist[d.x >> 7], 1);
    atomicAdd(&hist[d.y >> 7], 1);
    atomicAdd(&hist[d.z >> 7], 1);
    atomicAdd(&hist[d.w >> 7], 1);
  }
  __syncthreads();
  for (int i = tid; i < NBUCK; i += 256) {
    int c = hist[i];
    if (c) base[i] = atomicAdd(&bcur[i * CPAD], c);
  }
  __syncthreads();
  for (int i = tid; i < NBUCK; i += 256) hist[i] = 0;
  __syncthreads();
  for (int e = e0 + tid * 4; e < e1; e += 1024) {
    int4 d = *(const int4*)(dst + e);
    int4 s = *(const int4*)(src + e);
    int b, loc;
    b = d.x >> 7; loc = atomicAdd(&hist[b], 1);
    ebuf[base[b] + loc] = (u32)s.x | ((u32)(d.x & 127) << 17);
    b = d.y >> 7; loc = atomicAdd(&hist[b], 1);
    ebuf[base[b] + loc] = (u32)s.y | ((u32)(d.y & 127) << 17);
    b = d.z >> 7; loc = atomicAdd(&hist[b], 1);
    ebuf[base[b] + loc] = (u32)s.z | ((u32)(d.z & 127) << 17);
    b = d.w >> 7; loc = atomicAdd(&hist[b], 1);
    ebuf[base[b] + loc] = (u32)s.w | ((u32)(d.w & 127) << 17);
  }
}

__global__ __launch_bounds__(256) void binC_kernel(const u32* __restrict__ ebuf,
                                                   const int* __restrict__ bbase,
                                                   int* __restrict__ rs,
                                                   int* __restrict__ csr) {
  __shared__ int cnt[128], sc[128], cur[128];
  int b = blockIdx.x, tid = threadIdx.x;
  int e0 = bbase[b], e1 = bbase[b + 1];
  if (tid < 128) cnt[tid] = 0;
  __syncthreads();
  for (int e = e0 + tid; e < e1; e += 256) atomicAdd(&cnt[ebuf[e] >> 17], 1);
  __syncthreads();
  if (tid < 128) sc[tid] = cnt[tid];
  __syncthreads();
  for (int off = 1; off < 128; off <<= 1) {
    int t = 0;
    if (tid < 128 && tid >= off) t = sc[tid - off];
    __syncthreads();
    if (tid < 128) sc[tid] += t;
    __syncthreads();
  }
  if (tid < 128) {
    int gpos = e0 + sc[tid] - cnt[tid];
    int node = b * 128 + tid;
    if (node < NN) rs[node] = gpos;
    cur[tid] = gpos;
  }
  __syncthreads();
  for (int e = e0 + tid; e < e1; e += 256) {
    u32 p = ebuf[e];
    int pos = atomicAdd(&cur[p >> 17], 1);
    csr[pos] = (int)(p & 0x1FFFFu);
  }
}

// ---------------- prep: pack weights + zm pad init + x->f16 conv, one kernel ----------------
// wp layout: dst[((nb*KG + g)*16 + nn)*8 + e] = W[k=g*8+e][n=nb*16+nn], bias folded at k=95/159

__device__ __forceinline__ f16 pack_one(const float* __restrict__ W,
                                        const float* __restrict__ bias, int rel, int K, int Nc,
                                        int KG, int trans, int bslot) {
  int e = rel & 7, nn = (rel >> 3) & 15;
  int g = (rel >> 7) % KG, nb = (rel >> 7) / KG;
  int k = g * 8 + e, n = nb * 16 + nn;
  float v = 0.f;
  if (n < Nc) {
    if (k < K) v = trans ? W[n * K + k] : W[k * Nc + n];
    else if (k == bslot) v = bias[n];
  }
  return (f16)v;
}

__global__ __launch_bounds__(256) void prep_kernel(const float* __restrict__ x,
                                                   f16* __restrict__ xp,
                                                   f16* __restrict__ zm,
                                                   const float* __restrict__ w1,
                                                   const float* __restrict__ b1,
                                                   const float* __restrict__ w2,
                                                   const float* __restrict__ b2,
                                                   const float* __restrict__ wih,
                                                   const float* __restrict__ bih,
                                                   const float* __restrict__ whh,
                                                   const float* __restrict__ bhh,
                                                   const float* __restrict__ wc1,
                                                   const float* __restrict__ bc1,
                                                   const float* __restrict__ wc2,
                                                   const float* __restrict__ bc2,
                                                   f16* __restrict__ wp) {
  int b = blockIdx.x, tid = threadIdx.x;
  if (b < 470) {
    int i = b * 256 + tid;
    if (i >= 120320) return;
    f16 v;
    if (i < 7680) v = pack_one(w1, b1, i, 75, 75, 12, 0, 95);
    else if (i < 15360) v = pack_one(w2, b2, i - 7680, 75, 75, 12, 0, 95);
    else if (i < 38400) {
      int r = i - 15360, g = r / 7680;
      v = pack_one(wih + g * 5625, bih + g * 75, r - g * 7680, 75, 75, 12, 1, 95);
    } else if (i < 61440) {
      int r = i - 38400, g = r / 7680;
      v = pack_one(whh + g * 5625, bhh + g * 75, r - g * 7680, 75, 75, 12, 1, 95);
    } else if (i < 107520) {
      int rel = i - 61440;
      int e = rel & 7, nn = (rel >> 3) & 15;
      int g = (rel >> 7) % 36, nb = (rel >> 7) / 36;
      int q = g * 8 + e, buf = q / 96, kk = q - buf * 96, n = nb * 16 + nn;
      float f = 0.f;
      if (n < 150) {
        if (kk < 75) f = wc1[(buf * 75 + kk) * 150 + n];
        else if (kk == 95 && buf == 0) f = bc1[n];
      }
      v = (f16)f;
    } else v = pack_one(wc2, bc2, i - 107520, 150, 75, 20, 0, 159);
    wp[i] = v;
  } else if (b < 6722) {
    int i = (b - 470) * 256 + tid;   // N2*16 = 1600512 exactly
    int r = i >> 4, c = i & 15;
    zm[r * 96 + 80 + c] = (f16)(c == 15 ? 1.f : 0.f);
  } else {
    int i = (b - 6722) * 256 + tid;  // N2*96 = 9603072 exactly
    int r = i / 96, c = i - r * 96;
    float v = (r < NN && c < 75) ? x[r * 75 + c] : (c == 95 ? 1.f : 0.f);
    xp[i] = (f16)v;
  }
}

// ---------------- aggregation: wave per node, 10 lanes x 16B, 6 edges in flight ----------------

__global__ __launch_bounds__(256) void aggz_kernel(const f16* __restrict__ xc,
                                                   const int* __restrict__ rs,
                                                   const int* __restrict__ csr,
                                                   const float* __restrict__ eps,
                                                   f16* __restrict__ zm) {
  int tid = threadIdx.x;
  int l = tid & 63;
  int n = blockIdx.x * 4 + (tid >> 6);
  if (n >= NN) return;
  int s = l / 10, j = l - s * 10;
  int e0 = rs[n], e1 = rs[n + 1];
  float acc[8] = {0, 0, 0, 0, 0, 0, 0, 0};
  if (l < 60) {
#pragma unroll 4
    for (int e = e0 + s; e < e1; e += 6) {
      int sr = csr[e];
      f16x8 v = *(const f16x8*)(xc + sr * 96 + j * 8);
#pragma unroll
      for (int k = 0; k < 8; ++k) acc[k] += (float)v[k];
    }
  }
  int l1 = (l + 30) & 63, l2 = (l + 10) & 63, l3 = (l + 20) & 63;
#pragma unroll
  for (int k = 0; k < 8; ++k) {
    float t = __shfl(acc[k], l1, 64);
    if (l < 30) acc[k] += t;
    t = __shfl(acc[k], l2, 64);
    if (l < 10) acc[k] += t;
    t = __shfl(acc[k], l3, 64);
    if (l < 10) acc[k] += t;
  }
  if (l < 10) {
    f16x8 self = *(const f16x8*)(xc + n * 96 + j * 8);
    float ep = 1.f + eps[0];
    f16x8 o;
#pragma unroll
    for (int k = 0; k < 8; ++k) o[k] = (f16)(ep * (float)self[k] + acc[k]);
    *(f16x8*)(zm + n * 96 + j * 8) = o;
  }
}

// ---------------- fused GIN-MLP + GRU, register-lean per-nb pipeline ----------------
// All LDS tiles PER-WAVE; biases folded into weights (col95/k95, col159/k159 trick).

__global__ __launch_bounds__(256) void mlpgru_kernel(const f16* __restrict__ zm,
                                                     const f16* __restrict__ hcur,
                                                     const f16* __restrict__ w1p,
                                                     const f16* __restrict__ w2p,
                                                     const f16* __restrict__ wihp,
                                                     const f16* __restrict__ whhp,
                                                     f16* __restrict__ hb_out,
                                                     float* __restrict__ outx) {
  __shared__ f16 Ls[4][16 * 104];
  __shared__ f16 Hs[4][16 * 104];
  int tid = threadIdx.x;
  int w = tid >> 6, l = tid & 63, lm = l & 15, lg = l >> 4;
  int row0 = blockIdx.x * 64 + w * 16;
  const f16* ar = zm + (row0 + lm) * 96;
  const f16* hr = hcur + (row0 + lm) * 96;
  f16x8 a0 = *(const f16x8*)(ar + lg * 8);
  f16x8 a1 = *(const f16x8*)(ar + 32 + lg * 8);
  f16x8 a2 = *(const f16x8*)(ar + 64 + lg * 8);
  f16x8 h0 = *(const f16x8*)(hr + lg * 8);
  f16x8 h1 = *(const f16x8*)(hr + 32 + lg * 8);
  f16x8 h2 = *(const f16x8*)(hr + 64 + lg * 8);
  f16* Hd = Hs[w];
  *(f16x8*)(Hd + lm * 104 + lg * 8) = h0;
  *(f16x8*)(Hd + lm * 104 + 32 + lg * 8) = h1;
  *(f16x8*)(Hd + lm * 104 + 64 + lg * 8) = h2;
  f16* Ld = Ls[w];
  // --- MLP layer 1 (per-nb, 1 live accumulator)
#pragma unroll
  for (int nb = 0; nb < 5; ++nb) {
    const f16* bp = w1p + ((nb * 12 + lg) * 16 + lm) * 8;
    f32x4 acc = (f32x4){0.f, 0.f, 0.f, 0.f};
    acc = MFMA(a0, *(const f16x8*)bp, acc);
    acc = MFMA(a1, *(const f16x8*)(bp + 512), acc);
    acc = MFMA(a2, *(const f16x8*)(bp + 1024), acc);
#pragma unroll
    for (int r = 0; r < 4; ++r)
      Ld[(lg * 4 + r) * 104 + nb * 16 + lm] = (f16)fmaxf(acc[r], 0.f);
  }
#pragma unroll
  for (int c = 0; c < 4; ++c) {
    int col = 80 + lg * 4 + c;
    Ld[lm * 104 + col] = (f16)(col == 95 ? 1.f : 0.f);  // pad + bias-slot 1
  }
  // --- MLP layer 2 (per-nb)
  const f16* Lr = Ld + lm * 104;
  f16x8 c0 = *(const f16x8*)(Lr + lg * 8);
  f16x8 c1 = *(const f16x8*)(Lr + 32 + lg * 8);
  f16x8 c2 = *(const f16x8*)(Lr + 64 + lg * 8);
#pragma unroll
  for (int nb = 0; nb < 5; ++nb) {
    const f16* bp = w2p + ((nb * 12 + lg) * 16 + lm) * 8;
    f32x4 acc = (f32x4){0.f, 0.f, 0.f, 0.f};
    acc = MFMA(c0, *(const f16x8*)bp, acc);
    acc = MFMA(c1, *(const f16x8*)(bp + 512), acc);
    acc = MFMA(c2, *(const f16x8*)(bp + 1024), acc);
#pragma unroll
    for (int r = 0; r < 4; ++r)
      Ld[(lg * 4 + r) * 104 + nb * 16 + lm] = (f16)fmaxf(acc[r], 0.f);
  }
  // --- GRU per-nb: 4 gate accs live for ONE column block at a time (register diet)
  f16x8 am0 = *(const f16x8*)(Lr + lg * 8);
  f16x8 am1 = *(const f16x8*)(Lr + 32 + lg * 8);
  f16x8 am2 = *(const f16x8*)(Lr + 64 + lg * 8);
#pragma unroll 1
  for (int nb = 0; nb < 5; ++nb) {
    f32x4 rg = (f32x4){0.f, 0.f, 0.f, 0.f};
    f32x4 zg = rg, ni = rg, nh = rg;
#pragma unroll
    for (int s = 0; s < 3; ++s) {
      f16x8 ams = (s == 0) ? am0 : (s == 1) ? am1 : am2;
      f16x8 ahs = (s == 0) ? h0 : (s == 1) ? h1 : h2;
      int fo = ((nb * 12 + s * 4 + lg) * 16 + lm) * 8;
      rg = MFMA(ams, *(const f16x8*)(wihp + fo), rg);
      rg = MFMA(ahs, *(const f16x8*)(whhp + fo), rg);
      zg = MFMA(ams, *(const f16x8*)(wihp + 7680 + fo), zg);
      zg = MFMA(ahs, *(const f16x8*)(whhp + 7680 + fo), zg);
      ni = MFMA(ams, *(const f16x8*)(wihp + 15360 + fo), ni);
      nh = MFMA(ahs, *(const f16x8*)(whhp + 15360 + fo), nh);
    }
#pragma unroll
    for (int r = 0; r < 4; ++r) {
      int n = nb * 16 + lm;
      float hval = (float)Hd[(lg * 4 + r) * 104 + n];
      float rv = 1.f / (1.f + __expf(-rg[r]));
      float zv = 1.f / (1.f + __expf(-zg[r]));
      float u = ni[r] + rv * nh[r];
      float t = __expf(-2.f * fabsf(u));
      float nv = copysignf((1.f - t) / (1.f + t), u);
      float hp = zv * (hval - nv) + nv;
      Ld[(lg * 4 + r) * 104 + n] = (f16)hp;
    }
  }
  // --- vectorized coalesced writeback: 16 rows x 96 f16
#pragma unroll
  for (int k = 0; k < 3; ++k) {
    int p = l + 64 * k;
    int r = p / 12, sl = p - r * 12;
    f16x8 v = *(const f16x8*)(Ld + r * 104 + sl * 8);
    *(f16x8*)(hb_out + (row0 + r) * 96 + sl * 8) = v;
  }
  if (outx) {
    for (int k = 0; k < 19; ++k) {
      int p = l + 64 * k;
      int gi = row0 * 75 + p;
      if (p < 1200 && gi < NN * 75) {
        int r = p / 75, c = p - r * 75;
        outx[gi] = (float)Ld[r * 104 + c];
      }
    }
  }
}

// ---------------- fused readout (biases folded; r1 col159=1 -> bc2) ----------------

__global__ __launch_bounds__(256) void readout_kernel(const f16* __restrict__ hb0,
                                                      const f16* __restrict__ hb1,
                                                      const f16* __restrict__ hb2,
                                                      const f16* __restrict__ wc1p,
                                                      const f16* __restrict__ wc2p,
                                                      float* __restrict__ out) {
  __shared__ f16 Ls[4][16 * 168];
  int tid = threadIdx.x;
  int w = tid >> 6, l = tid & 63, lm = l & 15, lg = l >> 4;
  int row0 = blockIdx.x * 64 + w * 16;
  int row = row0 + lm;
  f16x8 a[9];
#pragma unroll
  for (int s = 0; s < 9; ++s) {
    const f16* hb = (s < 3) ? hb0 : (s < 6) ? hb1 : hb2;
    a[s] = *(const f16x8*)(hb + row * 96 + (4 * (s - (s / 3) * 3) + lg) * 8);
  }
  f16* Ld = Ls[w];
#pragma unroll
  for (int nb = 0; nb < 10; ++nb) {
    f32x4 acc = (f32x4){0.f, 0.f, 0.f, 0.f};
#pragma unroll
    for (int s = 0; s < 9; ++s)
      acc = MFMA(a[s], *(const f16x8*)(wc1p + ((nb * 36 + 4 * s + lg) * 16 + lm) * 8), acc);
#pragma unroll
    for (int r = 0; r < 4; ++r) {
      int n = nb * 16 + lm;
      float v = fmaxf(acc[r], 0.f);
      if (n >= 150) v = (n == 159) ? 1.f : 0.f;   // pad + bias slot
      Ld[(lg * 4 + r) * 168 + n] = (f16)v;
    }
  }
  const f16* Lr = Ls[w] + lm * 168;
  f16x8 a2[5];
#pragma unroll
  for (int s = 0; s < 5; ++s) a2[s] = *(const f16x8*)(Lr + s * 32 + lg * 8);
  f32x4 acc2[5];
#pragma unroll
  for (int nb = 0; nb < 5; ++nb) {
    acc2[nb] = (f32x4){0.f, 0.f, 0.f, 0.f};
#pragma unroll
    for (int s = 0; s < 5; ++s)
      acc2[nb] = MFMA(a2[s], *(const f16x8*)(wc2p + ((nb * 20 + s * 4 + lg) * 16 + lm) * 8),
                      acc2[nb]);
  }
  float* Lf = (float*)Ls[w];
#pragma unroll
  for (int nb = 0; nb < 5; ++nb)
#pragma unroll
    for (int r = 0; r < 4; ++r) {
      int n = nb * 16 + lm;
      if (n < 75) Lf[(lg * 4 + r) * 76 + n] = acc2[nb][r];
    }
  for (int k = 0; k < 19; ++k) {
    int p = l + 64 * k;
    int gi = row0 * 75 + p;
    if (p < 1200 && gi < NN * 75) {
      int r = p / 75, c = p - r * 75;
      out[gi] = Lf[r * 76 + c];
    }
  }
}

// ---------------- launch ----------------

extern "C" void kernel_launch(void* const* d_in, const int* in_sizes, int n_in,
                              void* d_out, int out_size, void* d_ws, size_t ws_size,
                              hipStream_t stream) {
  const float* x    = (const float*)d_in[0];
  const int*   ei   = (const int*)d_in[1];
  const float* eps  = (const float*)d_in[2];
  const float* w1   = (const float*)d_in[3];
  const float* b1   = (const float*)d_in[4];
  const float* w2   = (const float*)d_in[5];
  const float* b2   = (const float*)d_in[6];
  const float* w_ih = (const float*)d_in[7];
  const float* w_hh = (const float*)d_in[8];
  const float* b_ih = (const float*)d_in[9];
  const float* b_hh = (const float*)d_in[10];
  const float* wc1  = (const float*)d_in[11];
  const float* bc1  = (const float*)d_in[12];
  const float* wc2  = (const float*)d_in[13];
  const float* bc2  = (const float*)d_in[14];

  const int* srcv = ei;
  const int* dstv = ei + EE;

  float* out_x = (float*)d_out;              // N*75 final node states (fp32)
  float* out_r = out_x + NN * 75;            // N*75 readout (fp32)

  f16* zm   = (f16*)d_ws;                    // N2*96
  f16* x0   = zm + (size_t)N2 * 96;          // N2*96
  f16* hb0  = x0 + (size_t)N2 * 96;          // N2*96
  f16* hb1  = hb0 + (size_t)N2 * 96;         // N2*96
  f16* hb2  = hb1 + (size_t)N2 * 96;         // N2*96
  f16* wp   = hb2 + (size_t)N2 * 96;         // packed weights, 120320 f16
  f16* w1p  = wp;
  f16* w2p  = wp + 7680;
  f16* wihp = wp + 15360;                    // 3 gates x 7680
  f16* whhp = wp + 38400;
  f16* wc1p = wp + 61440;                    // 46080 (KG=36, NB=10)
  f16* wc2p = wp + 107520;                   // 12800
  u32* ebuf = (u32*)(wp + 120320);           // EE
  int* csr  = (int*)(ebuf + EE);             // EE
  int* rsv  = csr + EE;                      // NN+1
  int* bbase = rsv + NN + 1;                 // NBUCK+1
  int* bcur  = bbase + NBUCK + 1;            // NBUCK*CPAD
  int* bcnt  = bcur + NBUCK * CPAD;          // NBUCK*CPAD

  hipMemsetAsync(bcnt, 0, NBUCK * CPAD * sizeof(int), stream);
  bhist_kernel<<<512, 256, 0, stream>>>((const int4*)dstv, bcnt);
  bscan_kernel<<<1, 1024, 0, stream>>>(bcnt, bbase, bcur, rsv);
  binB_kernel<<<(EE + CHUNK - 1) / CHUNK, 256, 0, stream>>>(srcv, dstv, bcur, ebuf);
  binC_kernel<<<NBUCK, 256, 0, stream>>>(ebuf, bbase, rsv, csr);
  prep_kernel<<<44234, 256, 0, stream>>>(x, x0, zm, w1, b1, w2, b2, w_ih, b_ih,
                                         w_hh, b_hh, wc1, bc1, wc2, bc2, wp);

  int gb = N2 / 64;  // 1563
  f16* hbs[3] = {hb0, hb1, hb2};
  for (int it = 0; it < 3; ++it) {
    const f16* h = (it == 0) ? x0 : hbs[it - 1];
    aggz_kernel<<<25000, 256, 0, stream>>>(h, rsv, csr, eps, zm);
    mlpgru_kernel<<<gb, 256, 0, stream>>>(zm, h, w1p, w2p, wihp, whhp,
                                          hbs[it], (it == 2) ? out_x : nullptr);
  }
  readout_kernel<<<gb, 256, 0, stream>>>(hb0, hb1, hb2, wc1p, wc2p, out_r);
}

// Round 10
// 544.545 us; speedup vs baseline: 2.6082x; 1.0706x over previous
//
#include <hip/hip_runtime.h>

#define NN 100000
#define EE 3200000
#define N2 100032   // NN rounded up to 64
#define NBUCK 782   // ceil(NN/128)
#define CPAD 16     // counter padding (one per 64B line)
#define CHUNK 12288 // edges per binB block
#define CAP 5120    // fixed bucket capacity (mean 4096 + 16 sigma)

typedef _Float16 f16;
typedef _Float16 f16x8 __attribute__((ext_vector_type(8)));
typedef float f32x4 __attribute__((ext_vector_type(4)));
typedef unsigned int u32;

#define MFMA(a, b, c) __builtin_amdgcn_mfma_f32_16x16x32_f16((a), (b), (c), 0, 0, 0)

// ---------------- CSR build: fixed-capacity buckets (no counting pre-pass) ----------------

__global__ __launch_bounds__(256) void initcur_kernel(int* __restrict__ bcur) {
  int i = blockIdx.x * 256 + threadIdx.x;
  if (i < NBUCK) bcur[i * CPAD] = i * CAP;
}

__global__ __launch_bounds__(256) void binB_kernel(const int* __restrict__ src,
                                                   const int* __restrict__ dst,
                                                   int* __restrict__ bcur,
                                                   u32* __restrict__ ebuf) {
  __shared__ int hist[NBUCK];
  __shared__ int base[NBUCK];
  int tid = threadIdx.x;
  int e0 = blockIdx.x * CHUNK;
  int e1 = e0 + CHUNK;
  if (e1 > EE) e1 = EE;
  for (int i = tid; i < NBUCK; i += 256) hist[i] = 0;
  __syncthreads();
  for (int e = e0 + tid * 4; e < e1; e += 1024) {
    int4 d = *(const int4*)(dst + e);
    atomicAdd(&hist[d.x >> 7], 1);
    atomicAdd(&hist[d.y >> 7], 1);
    atomicAdd(&hist[d.z >> 7], 1);
    atomicAdd(&hist[d.w >> 7], 1);
  }
  __syncthreads();
  for (int i = tid; i < NBUCK; i += 256) {
    int c = hist[i];
    if (c) base[i] = atomicAdd(&bcur[i * CPAD], c);
  }
  __syncthreads();
  for (int i = tid; i < NBUCK; i += 256) hist[i] = 0;
  __syncthreads();
  for (int e = e0 + tid * 4; e < e1; e += 1024) {
    int4 d = *(const int4*)(dst + e);
    int4 s = *(const int4*)(src + e);
    int b, loc;
    b = d.x >> 7; loc = atomicAdd(&hist[b], 1);
    ebuf[base[b] + loc] = (u32)s.x | ((u32)(d.x & 127) << 17);
    b = d.y >> 7; loc = atomicAdd(&hist[b], 1);
    ebuf[base[b] + loc] = (u32)s.y | ((u32)(d.y & 127) << 17);
    b = d.z >> 7; loc = atomicAdd(&hist[b], 1);
    ebuf[base[b] + loc] = (u32)s.z | ((u32)(d.z & 127) << 17);
    b = d.w >> 7; loc = atomicAdd(&hist[b], 1);
    ebuf[base[b] + loc] = (u32)s.w | ((u32)(d.w & 127) << 17);
  }
}

__global__ __launch_bounds__(256) void binC_kernel(const u32* __restrict__ ebuf,
                                                   const int* __restrict__ bcur,
                                                   int* __restrict__ st,
                                                   int* __restrict__ ct,
                                                   int* __restrict__ csr) {
  __shared__ int cnt[128], sc[128], cur[128];
  int b = blockIdx.x, tid = threadIdx.x;
  int e0 = b * CAP;
  int e1 = bcur[b * CPAD];   // final cursor = bucket end
  if (tid < 128) cnt[tid] = 0;
  __syncthreads();
  for (int e = e0 + tid; e < e1; e += 256) atomicAdd(&cnt[ebuf[e] >> 17], 1);
  __syncthreads();
  if (tid < 128) sc[tid] = cnt[tid];
  __syncthreads();
  for (int off = 1; off < 128; off <<= 1) {
    int t = 0;
    if (tid < 128 && tid >= off) t = sc[tid - off];
    __syncthreads();
    if (tid < 128) sc[tid] += t;
    __syncthreads();
  }
  if (tid < 128) {
    int gpos = e0 + sc[tid] - cnt[tid];
    int node = b * 128 + tid;
    if (node < NN) {
      st[node] = gpos;
      ct[node] = cnt[tid];
    }
    cur[tid] = gpos;
  }
  __syncthreads();
  for (int e = e0 + tid; e < e1; e += 256) {
    u32 p = ebuf[e];
    int pos = atomicAdd(&cur[p >> 17], 1);
    csr[pos] = (int)(p & 0x1FFFFu);
  }
}

// ---------------- prep: pack weights (bias folded at k=95/159) + x->f16 conv ----------------

__device__ __forceinline__ f16 pack_one(const float* __restrict__ W,
                                        const float* __restrict__ bias, int rel, int K, int Nc,
                                        int KG, int trans, int bslot) {
  int e = rel & 7, nn = (rel >> 3) & 15;
  int g = (rel >> 7) % KG, nb = (rel >> 7) / KG;
  int k = g * 8 + e, n = nb * 16 + nn;
  float v = 0.f;
  if (n < Nc) {
    if (k < K) v = trans ? W[n * K + k] : W[k * Nc + n];
    else if (k == bslot) v = bias[n];
  }
  return (f16)v;
}

__global__ __launch_bounds__(256) void prep_kernel(const float* __restrict__ x,
                                                   f16* __restrict__ xp,
                                                   const float* __restrict__ w1,
                                                   const float* __restrict__ b1,
                                                   const float* __restrict__ w2,
                                                   const float* __restrict__ b2,
                                                   const float* __restrict__ wih,
                                                   const float* __restrict__ bih,
                                                   const float* __restrict__ whh,
                                                   const float* __restrict__ bhh,
                                                   const float* __restrict__ wc1,
                                                   const float* __restrict__ bc1,
                                                   const float* __restrict__ wc2,
                                                   const float* __restrict__ bc2,
                                                   f16* __restrict__ wp) {
  int b = blockIdx.x, tid = threadIdx.x;
  if (b < 470) {
    int i = b * 256 + tid;
    if (i >= 120320) return;
    f16 v;
    if (i < 7680) v = pack_one(w1, b1, i, 75, 75, 12, 0, 95);
    else if (i < 15360) v = pack_one(w2, b2, i - 7680, 75, 75, 12, 0, 95);
    else if (i < 38400) {
      int r = i - 15360, g = r / 7680;
      v = pack_one(wih + g * 5625, bih + g * 75, r - g * 7680, 75, 75, 12, 1, 95);
    } else if (i < 61440) {
      int r = i - 38400, g = r / 7680;
      v = pack_one(whh + g * 5625, bhh + g * 75, r - g * 7680, 75, 75, 12, 1, 95);
    } else if (i < 107520) {
      int rel = i - 61440;
      int e = rel & 7, nn = (rel >> 3) & 15;
      int g = (rel >> 7) % 36, nb = (rel >> 7) / 36;
      int q = g * 8 + e, buf = q / 96, kk = q - buf * 96, n = nb * 16 + nn;
      float f = 0.f;
      if (n < 150) {
        if (kk < 75) f = wc1[(buf * 75 + kk) * 150 + n];
        else if (kk == 95 && buf == 0) f = bc1[n];
      }
      v = (f16)f;
    } else v = pack_one(wc2, bc2, i - 107520, 150, 75, 20, 0, 159);
    wp[i] = v;
  } else {
    int i = (b - 470) * 256 + tid;  // N2*96 = 9603072 = 37512*256
    int r = i / 96, c = i - r * 96;
    float v = (r < NN && c < 75) ? x[r * 75 + c] : (c == 95 ? 1.f : 0.f);
    xp[i] = (f16)v;
  }
}

// ---------------- fused aggregation + GIN-MLP + GRU ----------------
// Wave owns 16 output rows. Gather: 6 groups x 10 lanes, each group one node's
// edge list SERIALLY (no shuffles), z written to the per-wave LDS tile; then
// MFMA reads A-frags from LDS. Biases folded (col95=1 trick). Per-wave tiles
// -> no __syncthreads.

__global__ __launch_bounds__(256) void fuse_kernel(const f16* __restrict__ hcur,
                                                   const int* __restrict__ st,
                                                   const int* __restrict__ ct,
                                                   const int* __restrict__ csr,
                                                   const float* __restrict__ eps,
                                                   const f16* __restrict__ w1p,
                                                   const f16* __restrict__ w2p,
                                                   const f16* __restrict__ wihp,
                                                   const f16* __restrict__ whhp,
                                                   f16* __restrict__ hb_out,
                                                   float* __restrict__ outx) {
  __shared__ f16 Ls[4][16 * 104];
  __shared__ f16 Hs[4][16 * 104];
  int tid = threadIdx.x;
  int w = tid >> 6, l = tid & 63, lm = l & 15, lg = l >> 4;
  int row0 = blockIdx.x * 64 + w * 16;
  f16* Ld = Ls[w];
  // --- gather phase: z = (1+eps)*h + sum_in h[src], straight into LDS
  int g = l / 10, j = l - g * 10;   // g in 0..6 (lanes 60..63 idle), j covers cols 8j..8j+7
  float ep = 1.f + eps[0];
#pragma unroll 1
  for (int r = 0; r < 3; ++r) {
    int idx = r * 6 + g;
    if (g < 6 && idx < 16) {
      int n = row0 + idx;
      bool valid = n < NN;
      int e = valid ? st[n] : 0;
      int eend = e + (valid ? ct[n] : 0);
      float acc[8] = {0, 0, 0, 0, 0, 0, 0, 0};
#pragma unroll 4
      for (; e < eend; ++e) {
        int sr = csr[e];
        f16x8 v = *(const f16x8*)(hcur + sr * 96 + j * 8);
#pragma unroll
        for (int k = 0; k < 8; ++k) acc[k] += (float)v[k];
      }
      f16x8 o;
      if (valid) {
        f16x8 self = *(const f16x8*)(hcur + n * 96 + j * 8);
#pragma unroll
        for (int k = 0; k < 8; ++k) o[k] = (f16)(ep * (float)self[k] + acc[k]);
      } else {
#pragma unroll
        for (int k = 0; k < 8; ++k) o[k] = (f16)0.f;
      }
      *(f16x8*)(Ld + idx * 104 + j * 8) = o;
    }
  }
  // pad cols 80..94 = 0, col 95 = 1 (bias slot)
#pragma unroll
  for (int c = 0; c < 4; ++c) {
    int col = 80 + lg * 4 + c;
    Ld[lm * 104 + col] = (f16)(col == 95 ? 1.f : 0.f);
  }
  // --- h fragments + epilogue stage
  const f16* hr = hcur + (row0 + lm) * 96;
  f16x8 h0 = *(const f16x8*)(hr + lg * 8);
  f16x8 h1 = *(const f16x8*)(hr + 32 + lg * 8);
  f16x8 h2 = *(const f16x8*)(hr + 64 + lg * 8);
  f16* Hd = Hs[w];
  *(f16x8*)(Hd + lm * 104 + lg * 8) = h0;
  *(f16x8*)(Hd + lm * 104 + 32 + lg * 8) = h1;
  *(f16x8*)(Hd + lm * 104 + 64 + lg * 8) = h2;
  // --- MLP layer 1 (A-frags from LDS z-tile)
  const f16* Lr = Ld + lm * 104;
  f16x8 a0 = *(const f16x8*)(Lr + lg * 8);
  f16x8 a1 = *(const f16x8*)(Lr + 32 + lg * 8);
  f16x8 a2 = *(const f16x8*)(Lr + 64 + lg * 8);
#pragma unroll
  for (int nb = 0; nb < 5; ++nb) {
    const f16* bp = w1p + ((nb * 12 + lg) * 16 + lm) * 8;
    f32x4 acc = (f32x4){0.f, 0.f, 0.f, 0.f};
    acc = MFMA(a0, *(const f16x8*)bp, acc);
    acc = MFMA(a1, *(const f16x8*)(bp + 512), acc);
    acc = MFMA(a2, *(const f16x8*)(bp + 1024), acc);
#pragma unroll
    for (int r = 0; r < 4; ++r)
      Ld[(lg * 4 + r) * 104 + nb * 16 + lm] = (f16)fmaxf(acc[r], 0.f);
  }
  // --- MLP layer 2
  f16x8 c0 = *(const f16x8*)(Lr + lg * 8);
  f16x8 c1 = *(const f16x8*)(Lr + 32 + lg * 8);
  f16x8 c2 = *(const f16x8*)(Lr + 64 + lg * 8);
#pragma unroll
  for (int nb = 0; nb < 5; ++nb) {
    const f16* bp = w2p + ((nb * 12 + lg) * 16 + lm) * 8;
    f32x4 acc = (f32x4){0.f, 0.f, 0.f, 0.f};
    acc = MFMA(c0, *(const f16x8*)bp, acc);
    acc = MFMA(c1, *(const f16x8*)(bp + 512), acc);
    acc = MFMA(c2, *(const f16x8*)(bp + 1024), acc);
#pragma unroll
    for (int r = 0; r < 4; ++r)
      Ld[(lg * 4 + r) * 104 + nb * 16 + lm] = (f16)fmaxf(acc[r], 0.f);
  }
  // --- GRU per-nb (register-lean)
  f16x8 am0 = *(const f16x8*)(Lr + lg * 8);
  f16x8 am1 = *(const f16x8*)(Lr + 32 + lg * 8);
  f16x8 am2 = *(const f16x8*)(Lr + 64 + lg * 8);
#pragma unroll 1
  for (int nb = 0; nb < 5; ++nb) {
    f32x4 rg = (f32x4){0.f, 0.f, 0.f, 0.f};
    f32x4 zg = rg, ni = rg, nh = rg;
#pragma unroll
    for (int s = 0; s < 3; ++s) {
      f16x8 ams = (s == 0) ? am0 : (s == 1) ? am1 : am2;
      f16x8 ahs = (s == 0) ? h0 : (s == 1) ? h1 : h2;
      int fo = ((nb * 12 + s * 4 + lg) * 16 + lm) * 8;
      rg = MFMA(ams, *(const f16x8*)(wihp + fo), rg);
      rg = MFMA(ahs, *(const f16x8*)(whhp + fo), rg);
      zg = MFMA(ams, *(const f16x8*)(wihp + 7680 + fo), zg);
      zg = MFMA(ahs, *(const f16x8*)(whhp + 7680 + fo), zg);
      ni = MFMA(ams, *(const f16x8*)(wihp + 15360 + fo), ni);
      nh = MFMA(ahs, *(const f16x8*)(whhp + 15360 + fo), nh);
    }
#pragma unroll
    for (int r = 0; r < 4; ++r) {
      int n = nb * 16 + lm;
      float hval = (float)Hd[(lg * 4 + r) * 104 + n];
      float rv = 1.f / (1.f + __expf(-rg[r]));
      float zv = 1.f / (1.f + __expf(-zg[r]));
      float u = ni[r] + rv * nh[r];
      float t = __expf(-2.f * fabsf(u));
      float nv = copysignf((1.f - t) / (1.f + t), u);
      float hp = zv * (hval - nv) + nv;
      Ld[(lg * 4 + r) * 104 + n] = (f16)hp;
    }
  }
  // --- vectorized coalesced writeback: 16 rows x 96 f16
#pragma unroll
  for (int k = 0; k < 3; ++k) {
    int p = l + 64 * k;
    int r = p / 12, sl = p - r * 12;
    f16x8 v = *(const f16x8*)(Ld + r * 104 + sl * 8);
    *(f16x8*)(hb_out + (row0 + r) * 96 + sl * 8) = v;
  }
  if (outx) {
    for (int k = 0; k < 19; ++k) {
      int p = l + 64 * k;
      int gi = row0 * 75 + p;
      if (p < 1200 && gi < NN * 75) {
        int r = p / 75, c = p - r * 75;
        outx[gi] = (float)Ld[r * 104 + c];
      }
    }
  }
}

// ---------------- fused readout (biases folded; r1 col159=1 -> bc2) ----------------

__global__ __launch_bounds__(256) void readout_kernel(const f16* __restrict__ hb0,
                                                      const f16* __restrict__ hb1,
                                                      const f16* __restrict__ hb2,
                                                      const f16* __restrict__ wc1p,
                                                      const f16* __restrict__ wc2p,
                                                      float* __restrict__ out) {
  __shared__ f16 Ls[4][16 * 168];
  int tid = threadIdx.x;
  int w = tid >> 6, l = tid & 63, lm = l & 15, lg = l >> 4;
  int row0 = blockIdx.x * 64 + w * 16;
  int row = row0 + lm;
  f16x8 a[9];
#pragma unroll
  for (int s = 0; s < 9; ++s) {
    const f16* hb = (s < 3) ? hb0 : (s < 6) ? hb1 : hb2;
    a[s] = *(const f16x8*)(hb + row * 96 + (4 * (s - (s / 3) * 3) + lg) * 8);
  }
  f16* Ld = Ls[w];
#pragma unroll
  for (int nb = 0; nb < 10; ++nb) {
    f32x4 acc = (f32x4){0.f, 0.f, 0.f, 0.f};
#pragma unroll
    for (int s = 0; s < 9; ++s)
      acc = MFMA(a[s], *(const f16x8*)(wc1p + ((nb * 36 + 4 * s + lg) * 16 + lm) * 8), acc);
#pragma unroll
    for (int r = 0; r < 4; ++r) {
      int n = nb * 16 + lm;
      float v = fmaxf(acc[r], 0.f);
      if (n >= 150) v = (n == 159) ? 1.f : 0.f;
      Ld[(lg * 4 + r) * 168 + n] = (f16)v;
    }
  }
  const f16* Lr = Ls[w] + lm * 168;
  f16x8 a2[5];
#pragma unroll
  for (int s = 0; s < 5; ++s) a2[s] = *(const f16x8*)(Lr + s * 32 + lg * 8);
  f32x4 acc2[5];
#pragma unroll
  for (int nb = 0; nb < 5; ++nb) {
    acc2[nb] = (f32x4){0.f, 0.f, 0.f, 0.f};
#pragma unroll
    for (int s = 0; s < 5; ++s)
      acc2[nb] = MFMA(a2[s], *(const f16x8*)(wc2p + ((nb * 20 + s * 4 + lg) * 16 + lm) * 8),
                      acc2[nb]);
  }
  float* Lf = (float*)Ls[w];
#pragma unroll
  for (int nb = 0; nb < 5; ++nb)
#pragma unroll
    for (int r = 0; r < 4; ++r) {
      int n = nb * 16 + lm;
      if (n < 75) Lf[(lg * 4 + r) * 76 + n] = acc2[nb][r];
    }
  for (int k = 0; k < 19; ++k) {
    int p = l + 64 * k;
    int gi = row0 * 75 + p;
    if (p < 1200 && gi < NN * 75) {
      int r = p / 75, c = p - r * 75;
      out[gi] = Lf[r * 76 + c];
    }
  }
}

// ---------------- launch ----------------

extern "C" void kernel_launch(void* const* d_in, const int* in_sizes, int n_in,
                              void* d_out, int out_size, void* d_ws, size_t ws_size,
                              hipStream_t stream) {
  const float* x    = (const float*)d_in[0];
  const int*   ei   = (const int*)d_in[1];
  const float* eps  = (const float*)d_in[2];
  const float* w1   = (const float*)d_in[3];
  const float* b1   = (const float*)d_in[4];
  const float* w2   = (const float*)d_in[5];
  const float* b2   = (const float*)d_in[6];
  const float* w_ih = (const float*)d_in[7];
  const float* w_hh = (const float*)d_in[8];
  const float* b_ih = (const float*)d_in[9];
  const float* b_hh = (const float*)d_in[10];
  const float* wc1  = (const float*)d_in[11];
  const float* bc1  = (const float*)d_in[12];
  const float* wc2  = (const float*)d_in[13];
  const float* bc2  = (const float*)d_in[14];

  const int* srcv = ei;
  const int* dstv = ei + EE;

  float* out_x = (float*)d_out;              // N*75 final node states (fp32)
  float* out_r = out_x + NN * 75;            // N*75 readout (fp32)

  f16* x0   = (f16*)d_ws;                    // N2*96
  f16* hb0  = x0 + (size_t)N2 * 96;          // N2*96
  f16* hb1  = hb0 + (size_t)N2 * 96;         // N2*96
  f16* hb2  = hb1 + (size_t)N2 * 96;         // N2*96
  f16* wp   = hb2 + (size_t)N2 * 96;         // packed weights, 120320 f16
  f16* w1p  = wp;
  f16* w2p  = wp + 7680;
  f16* wihp = wp + 15360;                    // 3 gates x 7680
  f16* whhp = wp + 38400;
  f16* wc1p = wp + 61440;                    // 46080 (KG=36, NB=10)
  f16* wc2p = wp + 107520;                   // 12800
  u32* ebuf = (u32*)(wp + 120320);           // NBUCK*CAP
  int* csr  = (int*)(ebuf + (size_t)NBUCK * CAP);  // NBUCK*CAP
  int* st   = csr + (size_t)NBUCK * CAP;     // NN
  int* ctv  = st + NN;                       // NN
  int* bcur = ctv + NN;                      // NBUCK*CPAD

  initcur_kernel<<<4, 256, 0, stream>>>(bcur);
  binB_kernel<<<(EE + CHUNK - 1) / CHUNK, 256, 0, stream>>>(srcv, dstv, bcur, ebuf);
  binC_kernel<<<NBUCK, 256, 0, stream>>>(ebuf, bcur, st, ctv, csr);
  prep_kernel<<<37982, 256, 0, stream>>>(x, x0, w1, b1, w2, b2, w_ih, b_ih,
                                         w_hh, b_hh, wc1, bc1, wc2, bc2, wp);

  int gb = N2 / 64;  // 1563
  f16* hbs[3] = {hb0, hb1, hb2};
  for (int it = 0; it < 3; ++it) {
    const f16* h = (it == 0) ? x0 : hbs[it - 1];
    fuse_kernel<<<gb, 256, 0, stream>>>(h, st, ctv, csr, eps, w1p, w2p, wihp, whhp,
                                        hbs[it], (it == 2) ? out_x : nullptr);
  }
  readout_kernel<<<gb, 256, 0, stream>>>(hb0, hb1, hb2, wc1p, wc2p, out_r);
}